// Round 18
// baseline (247.091 us; speedup 1.0000x reference)
//
#include <hip/hip_runtime.h>

#define NN 100000
#define EE 1600000
#define NF 256
#define NH 128

#define BK 98        // buckets of 1024 nodes
#define BNODE 1024
#define CHUNK 4096
#define NCHUNK ((EE + CHUNK - 1) / CHUNK)  // 391
#define CAP 24576    // per-bucket capacity (counts ~16327±128; huge margin)

typedef unsigned int u32;
typedef unsigned short u16;
typedef __attribute__((ext_vector_type(8))) short short8;
typedef __attribute__((ext_vector_type(4))) float f32x4;

static __device__ __forceinline__ u16 f2bf(float f) {
  u32 u = __float_as_uint(f);
  u32 r = (u + 0x7FFFu + ((u >> 16) & 1u)) >> 16;
  return (u16)r;
}
static __device__ __forceinline__ float bflo(u32 u) { return __uint_as_float(u << 16); }
static __device__ __forceinline__ float bfhi(u32 u) { return __uint_as_float(u & 0xFFFF0000u); }
static __device__ __forceinline__ float bf2f(u16 h) { return __uint_as_float(((u32)h) << 16); }

// ============ k_p1s: blocks 0..390 = edge binning; block 391 = spectral ====
// Spec uses GLOBAL scratch (L2-hot, 1 block) so the kernel's LDS stays 22KB
// and p1 keeps 4 blocks/CU (launch_bounds caps VGPR at 128).
__global__ __launch_bounds__(256, 4) void k_p1s(const int* __restrict__ row,
                                                const int* __restrict__ col,
                                                u32* __restrict__ gcur,
                                                u32* __restrict__ binned,
                                                const float* __restrict__ W,
                                                u16* __restrict__ Wt2,
                                                u16* __restrict__ Wtg,
                                                u16* __restrict__ Mg0,
                                                u16* __restrict__ Mg1,
                                                float* __restrict__ sig) {
  __shared__ __align__(16) char SM[22784];
  int t = threadIdx.x;

  if (blockIdx.x < NCHUNK) {
    // ---------------- p1: counting-sort edges into padded buckets ----------
    u32* keybuf = (u32*)SM;                                  // 16 KB
    unsigned char* bktbuf = (unsigned char*)(SM + 16384);    // 4 KB
    u32* hist = (u32*)(SM + 20480);
    u32* lstart = (u32*)(SM + 20992);
    u32* lofs = (u32*)(SM + 21504);
    u32* gb = (u32*)(SM + 22016);
    if (t < BK) hist[t] = 0;
    __syncthreads();
    int e0 = blockIdx.x * CHUNK;
    int n = min(CHUNK, EE - e0);
    for (int i = t; i < n; i += 256) {
      u32 d = (u32)col[e0 + i];
      atomicAdd(&hist[d >> 10], 1u);
    }
    __syncthreads();
    if (t == 0) {
      u32 s = 0;
      for (int b = 0; b < BK; b++) { lstart[b] = s; lofs[b] = s; s += hist[b]; }
    }
    __syncthreads();
    if (t < BK && hist[t]) gb[t] = (u32)t * CAP + atomicAdd(&gcur[t], hist[t]);
    __syncthreads();
    for (int i = t; i < n; i += 256) {
      u32 d = (u32)col[e0 + i];
      u32 s = (u32)row[e0 + i];
      u32 b = d >> 10;
      u32 p = atomicAdd(&lofs[b], 1u);
      keybuf[p] = ((d & 1023u) << 17) | s;
      bktbuf[p] = (unsigned char)b;
    }
    __syncthreads();
    for (int i = t; i < n; i += 256) {
      u32 b = bktbuf[i];
      binned[gb[b] + ((u32)i - lstart[b])] = keybuf[i];
    }
    return;
  }

  // ---------------- spec: spectral norm + Wt2, global-scratch matrices -----
  float* diag = (float*)SM;            // 128 f
  float* red = (float*)(SM + 512);     // 256 f
  float* uvec = (float*)(SM + 1536);   // 128 f
  int* jdx = (int*)(SM + 2048);        // 128 i
  float* itrS = (float*)(SM + 2560);
  int* jmS = (int*)(SM + 2564);
  int l = t & 63, w = t >> 6;
  int p = l & 15, q = l >> 4;

  // Wt2 fragment-permuted dump, direct from W:
  // Wt2[u32 u] = {W[k][c], W[k+1][c]}, c=n*16+(ll&15), k=ks*32+(ll>>4)*8+j
  for (int u = t; u < 16384; u += 256) {
    int h = u * 2;
    int n = h >> 12;
    int rem = h & 4095;
    int ks = rem >> 9;
    int rem2 = rem & 511;
    int ll = rem2 >> 3;
    int j = rem2 & 7;
    int c = n * 16 + (ll & 15);
    int k = ks * 32 + ((ll >> 4) << 3) + j;
    u32 lo = f2bf(W[k * NH + c]);
    u32 hi = f2bf(W[(k + 1) * NH + c]);
    ((u32*)Wt2)[u] = lo | (hi << 16);
  }
  // Wtg: bf16 Wt rows [c][k] (c-major, 256 bf16/row), coalesced W reads
  for (int idx = t; idx < NF * NH; idx += 256) {
    int c = idx & 127, k = idx >> 7;
    Wtg[c * 256 + k] = f2bf(W[k * NH + c]);
  }
  __threadfence();
  __syncthreads();

  // gram via MFMA: frags straight from Wtg (global, L2-hot)
  f32x4 acc[2][8] = {};
#pragma unroll
  for (int ks = 0; ks < 8; ks++) {
    int kb = ks * 32 + q * 8;
    short8 afr[2], bfr[8];
#pragma unroll
    for (int m = 0; m < 2; m++) {
      int ra = w * 32 + m * 16 + p;
      afr[m] = *(const short8*)&Wtg[ra * 256 + kb];
    }
#pragma unroll
    for (int n = 0; n < 8; n++) {
      int r = n * 16 + p;
      bfr[n] = *(const short8*)&Wtg[r * 256 + kb];
    }
#pragma unroll
    for (int m = 0; m < 2; m++)
#pragma unroll
      for (int n = 0; n < 8; n++)
        acc[m][n] = __builtin_amdgcn_mfma_f32_16x16x32_bf16(afr[m], bfr[n], acc[m][n], 0, 0, 0);
  }
#pragma unroll
  for (int m = 0; m < 2; m++)
#pragma unroll
    for (int n = 0; n < 8; n++)
#pragma unroll
      for (int g = 0; g < 4; g++) {
        int r = w * 32 + m * 16 + q * 4 + g;
        int c = n * 16 + p;
        if (r == c) diag[r] = acc[m][n][g];
      }
  __syncthreads();
  if (t < 128) red[t] = diag[t];
  __syncthreads();
  for (int d = 64; d > 0; d >>= 1) { if (t < d) red[t] += red[t + d]; __syncthreads(); }
  if (t == 0) itrS[0] = 1.0f / red[0];
  __syncthreads();
  {
    float itr = itrS[0];
#pragma unroll
    for (int m = 0; m < 2; m++)
#pragma unroll
      for (int n = 0; n < 8; n++)
#pragma unroll
        for (int g = 0; g < 4; g++) {
          int r = w * 32 + m * 16 + q * 4 + g;
          int c = n * 16 + p;
          Mg0[r * 128 + c] = f2bf(acc[m][n][g] * itr);
        }
  }
  __threadfence();

  // 8 trace-normalized MFMA squarings (bf16, global ping-pong)
  u16* src = Mg0;
  u16* dst = Mg1;
  for (int s = 0; s < 8; s++) {
    __syncthreads();
    f32x4 mac[2][8] = {};
#pragma unroll
    for (int ks = 0; ks < 4; ks++) {
      int kb = ks * 32 + q * 8;
      short8 afr[2], bfr[8];
#pragma unroll
      for (int m = 0; m < 2; m++) {
        int ra = w * 32 + m * 16 + p;
        afr[m] = *(const short8*)&src[ra * 128 + kb];
      }
#pragma unroll
      for (int n = 0; n < 8; n++) {
        int r = n * 16 + p;
        bfr[n] = *(const short8*)&src[r * 128 + kb];
      }
#pragma unroll
      for (int m = 0; m < 2; m++)
#pragma unroll
        for (int n = 0; n < 8; n++)
          mac[m][n] = __builtin_amdgcn_mfma_f32_16x16x32_bf16(afr[m], bfr[n], mac[m][n], 0, 0, 0);
    }
#pragma unroll
    for (int m = 0; m < 2; m++)
#pragma unroll
      for (int n = 0; n < 8; n++)
#pragma unroll
        for (int g = 0; g < 4; g++) {
          int r = w * 32 + m * 16 + q * 4 + g;
          int c = n * 16 + p;
          if (r == c) diag[r] = mac[m][n][g];
        }
    __syncthreads();
    if (t < 128) red[t] = diag[t];
    __syncthreads();
    for (int d = 64; d > 0; d >>= 1) { if (t < d) red[t] += red[t + d]; __syncthreads(); }
    if (t == 0) itrS[0] = 1.0f / red[0];
    __syncthreads();
    float it2 = itrS[0];
#pragma unroll
    for (int m = 0; m < 2; m++)
#pragma unroll
      for (int n = 0; n < 8; n++)
#pragma unroll
        for (int g = 0; g < 4; g++) {
          int r = w * 32 + m * 16 + q * 4 + g;
          int c = n * 16 + p;
          dst[r * 128 + c] = f2bf(mac[m][n][g] * it2);
        }
    __threadfence();
    u16* tmp = src; src = dst; dst = tmp;
  }
  __syncthreads();

  // parallel argmax of diag -> u = row jm of M
  if (t < 128) { red[t] = diag[t]; jdx[t] = t; }
  __syncthreads();
  for (int d = 64; d > 0; d >>= 1) {
    if (t < d && red[t + d] > red[t]) { red[t] = red[t + d]; jdx[t] = jdx[t + d]; }
    __syncthreads();
  }
  if (t == 0) jmS[0] = jdx[0];
  __syncthreads();
  int jm = jmS[0];
  if (t < 128) uvec[t] = bf2f(src[jm * 128 + t]);
  __syncthreads();
  // Rayleigh on original W: lambda1 = |W u|^2 / |u|^2
  {
    float a2 = 0.f;
    const float* wr = &W[t * NH];
    for (int k = 0; k < NH; k++) a2 += wr[k] * uvec[k];
    red[t] = a2 * a2;
  }
  __syncthreads();
  for (int d = 128; d > 0; d >>= 1) { if (t < d) red[t] += red[t + d]; __syncthreads(); }
  if (t == 0) itrS[0] = red[0];
  __syncthreads();
  float num = itrS[0];
  if (t < 128) red[t] = uvec[t] * uvec[t];
  __syncthreads();
  for (int d = 64; d > 0; d >>= 1) { if (t < d) red[t] += red[t + d]; __syncthreads(); }
  if (t == 0) sig[0] = rsqrtf(num / red[0]);  // 1/sigma
}

// ---------------- P2: per-bucket counting sort in LDS (padded base) --------
__global__ __launch_bounds__(1024) void k_p2(const u32* __restrict__ binned,
                                             const u32* __restrict__ gcur,
                                             uint2* __restrict__ offdeg,
                                             float* __restrict__ dinv,
                                             int* __restrict__ csr) {
  __shared__ u32 hist[BNODE];
  __shared__ u32 loff[BNODE];
  __shared__ u32 cur[BNODE];
  __shared__ u32 stage[CAP];
  int b = blockIdx.x, t = threadIdx.x;
  u32 base = (u32)b * CAP;
  u32 cnt = gcur[b];
  hist[t] = 0;
  __syncthreads();
  for (u32 i = t; i < cnt; i += BNODE) {
    u32 key = binned[base + i];
    atomicAdd(&hist[key >> 17], 1u);
  }
  __syncthreads();
  u32 v = hist[t];
  loff[t] = v;
  __syncthreads();
  for (int d = 1; d < BNODE; d <<= 1) {
    u32 x = loff[t];
    u32 y = (t >= d) ? loff[t - d] : 0u;
    __syncthreads();
    loff[t] = x + y;
    __syncthreads();
  }
  u32 ex = loff[t] - v;
  cur[t] = ex;
  int g = b * BNODE + t;
  if (g < NN) {
    offdeg[g] = make_uint2(base + ex, base + ex + v);
    dinv[g] = rsqrtf((float)(v + 1u));
  }
  __syncthreads();
  if (cnt <= CAP) {
    for (u32 i = t; i < cnt; i += BNODE) {
      u32 key = binned[base + i];
      u32 p = atomicAdd(&cur[key >> 17], 1u);
      stage[p] = key & 0x1FFFFu;
    }
    __syncthreads();
    for (u32 i = t; i < cnt; i += BNODE) csr[base + i] = (int)stage[i];
  } else {
    for (u32 i = t; i < cnt; i += BNODE) {
      u32 key = binned[base + i];
      u32 p = atomicAdd(&cur[key >> 17], 1u);
      csr[base + p] = (int)(key & 0x1FFFFu);
    }
  }
}

// ------- MFMA GEMM (R17-exact): coalesced LDS-staged x, permuted Wt2 -------
__global__ __launch_bounds__(256) void k_mfma(const float* __restrict__ x,
                                              const u16* __restrict__ Wt2,
                                              const float* __restrict__ dinv,
                                              u16* __restrict__ hs) {
  __shared__ __align__(16) char LB[65536];
  int t = threadIdx.x;
  int l = t & 63, w = t >> 6;
  int row0 = blockIdx.x * 128;
  int lr = l & 15;
  int lk = (l >> 4) * 8;

  const float4* x4 = (const float4*)x;
#pragma unroll 8
  for (int i = t; i < 128 * 64; i += 256) {
    int r = i >> 6;
    int cq = i & 63;
    int gr = row0 + r;
    if (gr >= NN) gr = NN - 1;
    float4 v = x4[(size_t)gr * 64 + cq];
    uint2 wv;
    wv.x = (u32)f2bf(v.x) | ((u32)f2bf(v.y) << 16);
    wv.y = (u32)f2bf(v.z) | ((u32)f2bf(v.w) << 16);
    int kb = cq * 8;
    *(uint2*)(LB + r * 512 + (kb ^ ((r & 7) << 4))) = wv;
  }
  __syncthreads();

  int rbase = w * 32;
  f32x4 acc[2][8] = {};
#pragma unroll
  for (int ks = 0; ks < 8; ks++) {
    short8 bfr[8];
#pragma unroll
    for (int n = 0; n < 8; n++)
      bfr[n] = *(const short8*)&Wt2[(size_t)(((n * 8 + ks) * 64) + l) * 8];
    short8 afr[2];
#pragma unroll
    for (int m = 0; m < 2; m++) {
      int r = rbase + m * 16 + lr;
      int kb = (ks * 32 + lk) * 2;
      afr[m] = *(const short8*)(LB + r * 512 + (kb ^ ((r & 7) << 4)));
    }
#pragma unroll
    for (int m = 0; m < 2; m++)
#pragma unroll
      for (int n = 0; n < 8; n++)
        acc[m][n] = __builtin_amdgcn_mfma_f32_16x16x32_bf16(afr[m], bfr[n], acc[m][n], 0, 0, 0);
  }

  __syncthreads();
  u16* tile = (u16*)LB;
#pragma unroll
  for (int m = 0; m < 2; m++) {
    int rbl = w * 32 + m * 16 + (l >> 4) * 4;
    float dv[4];
#pragma unroll
    for (int g = 0; g < 4; g++) {
      int r = row0 + rbl + g;
      dv[g] = (r < NN) ? dinv[r] : 0.f;
    }
#pragma unroll
    for (int n = 0; n < 8; n++)
#pragma unroll
      for (int g = 0; g < 4; g++)
        tile[(rbl + g) * 128 + n * 16 + lr] = f2bf(acc[m][n][g] * dv[g]);
  }
  __syncthreads();
  const uint4* tl = (const uint4*)tile;
  size_t outb = (size_t)row0 * NH;
#pragma unroll
  for (int k = 0; k < 8; k++) {
    int u = t + k * 256;
    if (row0 + (u >> 4) < NN) *(uint4*)&hs[outb + (size_t)u * 8] = tl[u];
  }
}

// -------- gather: R14-exact (wave per node, 8-deep MLP unroll) -------------
__global__ __launch_bounds__(256) void k_gather(const u16* __restrict__ hs,
                                                const int* __restrict__ csr,
                                                const uint2* __restrict__ offdeg,
                                                const float* __restrict__ dinv,
                                                const float* __restrict__ b,
                                                const float* __restrict__ pa,
                                                const float* __restrict__ sig,
                                                float* __restrict__ out) {
  int wid = threadIdx.x >> 6;
  int lane = threadIdx.x & 63;
  int n = blockIdx.x * 4 + wid;
  if (n >= NN) return;
  uint2 od = offdeg[n];
  u32 s0 = od.x, s1 = od.y;
  const u32* hrow = (const u32*)hs;
  float ax, ay;
  {
    u32 u = hrow[(size_t)n * 64 + lane];  // self-loop term
    ax = bflo(u); ay = bfhi(u);
  }
  u32 e = s0;
  for (; e + 8 <= s1; e += 8) {
    int i0 = csr[e],     i1 = csr[e + 1], i2 = csr[e + 2], i3 = csr[e + 3];
    int i4 = csr[e + 4], i5 = csr[e + 5], i6 = csr[e + 6], i7 = csr[e + 7];
    u32 u0 = hrow[(size_t)i0 * 64 + lane];
    u32 u1 = hrow[(size_t)i1 * 64 + lane];
    u32 u2 = hrow[(size_t)i2 * 64 + lane];
    u32 u3 = hrow[(size_t)i3 * 64 + lane];
    u32 u4 = hrow[(size_t)i4 * 64 + lane];
    u32 u5 = hrow[(size_t)i5 * 64 + lane];
    u32 u6 = hrow[(size_t)i6 * 64 + lane];
    u32 u7 = hrow[(size_t)i7 * 64 + lane];
    ax += bflo(u0) + bflo(u1) + bflo(u2) + bflo(u3)
        + bflo(u4) + bflo(u5) + bflo(u6) + bflo(u7);
    ay += bfhi(u0) + bfhi(u1) + bfhi(u2) + bfhi(u3)
        + bfhi(u4) + bfhi(u5) + bfhi(u6) + bfhi(u7);
  }
  for (; e + 4 <= s1; e += 4) {
    int i0 = csr[e], i1 = csr[e + 1], i2 = csr[e + 2], i3 = csr[e + 3];
    u32 u0 = hrow[(size_t)i0 * 64 + lane];
    u32 u1 = hrow[(size_t)i1 * 64 + lane];
    u32 u2 = hrow[(size_t)i2 * 64 + lane];
    u32 u3 = hrow[(size_t)i3 * 64 + lane];
    ax += bflo(u0) + bflo(u1) + bflo(u2) + bflo(u3);
    ay += bfhi(u0) + bfhi(u1) + bfhi(u2) + bfhi(u3);
  }
  for (; e < s1; e++) {
    u32 u = hrow[(size_t)csr[e] * 64 + lane];
    ax += bflo(u); ay += bfhi(u);
  }
  float dv = dinv[n] * sig[0];
  float2 bb = *(const float2*)&b[lane * 2];
  float a = pa[0];
  float v0 = ax * dv + bb.x;
  float v1 = ay * dv + bb.y;
  float2 o;
  o.x = v0 > 0.f ? v0 : a * v0;
  o.y = v1 > 0.f ? v1 : a * v1;
  *(float2*)&out[(size_t)n * NH + lane * 2] = o;
}

// ---------------- launch ----------------
extern "C" void kernel_launch(void* const* d_in, const int* in_sizes, int n_in,
                              void* d_out, int out_size, void* d_ws, size_t ws_size,
                              hipStream_t stream) {
  const float* x = (const float*)d_in[0];
  const int* ei = (const int*)d_in[1];
  const float* W = (const float*)d_in[2];
  const float* b = (const float*)d_in[3];
  const float* pa = (const float*)d_in[4];
  float* out = (float*)d_out;
  const int* row = ei;
  const int* col = ei + EE;

  char* base = (char*)d_ws;
  size_t o = 0;
  auto alloc = [&](size_t bytes) -> void* {
    void* p = base + o;
    o += (bytes + 63) & ~(size_t)63;
    return p;
  };
  u32* gcur = (u32*)alloc(BK * 4);
  float* sig = (float*)alloc(64);
  float* dinv = (float*)alloc((size_t)NN * 4);
  uint2* offdeg = (uint2*)alloc((size_t)NN * 8);
  u32* binned = (u32*)alloc((size_t)BK * CAP * 4);
  int* csr = (int*)alloc((size_t)BK * CAP * 4);
  u16* Wt2 = (u16*)alloc((size_t)NF * NH * 2);
  u16* Wtg = (u16*)alloc((size_t)NF * NH * 2);
  u16* Mg0 = (u16*)alloc((size_t)NH * NH * 2);
  u16* Mg1 = (u16*)alloc((size_t)NH * NH * 2);
  u16* hs = (u16*)alloc((size_t)NN * NH * 2);
  (void)ws_size; (void)in_sizes; (void)n_in; (void)out_size;

  hipMemsetAsync(gcur, 0, BK * 4, stream);
  k_p1s<<<NCHUNK + 1, 256, 0, stream>>>(row, col, gcur, binned, W, Wt2, Wtg,
                                        Mg0, Mg1, sig);
  k_p2<<<BK, BNODE, 0, stream>>>(binned, gcur, offdeg, dinv, csr);
  k_mfma<<<(NN + 127) / 128, 256, 0, stream>>>(x, Wt2, dinv, hs);
  k_gather<<<(NN + 3) / 4, 256, 0, stream>>>(hs, csr, offdeg, dinv, b, pa, sig, out);
}

// Round 19
// 240.288 us; speedup vs baseline: 1.0283x; 1.0283x over previous
//
#include <hip/hip_runtime.h>

#define NN 100000
#define EE 1600000
#define NF 256
#define NH 128

#define BK 98        // buckets of 1024 nodes
#define BNODE 1024
#define CHUNK 4096
#define NCHUNK ((EE + CHUNK - 1) / CHUNK)  // 391
#define CAP 24576    // per-bucket capacity (counts ~16327±128; huge margin)

typedef unsigned int u32;
typedef unsigned short u16;
typedef __attribute__((ext_vector_type(8))) short short8;
typedef __attribute__((ext_vector_type(4))) float f32x4;

static __device__ __forceinline__ u16 f2bf(float f) {
  u32 u = __float_as_uint(f);
  u32 r = (u + 0x7FFFu + ((u >> 16) & 1u)) >> 16;
  return (u16)r;
}
static __device__ __forceinline__ float bflo(u32 u) { return __uint_as_float(u << 16); }
static __device__ __forceinline__ float bfhi(u32 u) { return __uint_as_float(u & 0xFFFF0000u); }
static __device__ __forceinline__ float bf2f(u16 h) { return __uint_as_float(((u32)h) << 16); }

// ============ k_p1s: blocks 0..390 = edge binning; block 391 = spectral ====
// Spec uses GLOBAL scratch (L2-hot, 1 block); kernel LDS stays 22.5KB.
// launch_bounds(256,3) -> 170 VGPR cap: spec branch (~150) does NOT spill
// (R18's (256,4)=128 cap spilled -> 140us straggler), p1 gets 3 blocks/CU.
__global__ __launch_bounds__(256, 3) void k_p1s(const int* __restrict__ row,
                                                const int* __restrict__ col,
                                                u32* __restrict__ gcur,
                                                u32* __restrict__ binned,
                                                const float* __restrict__ W,
                                                u16* __restrict__ Wt2,
                                                u16* __restrict__ Wtg,
                                                u16* __restrict__ Mg0,
                                                u16* __restrict__ Mg1,
                                                float* __restrict__ sig) {
  __shared__ __align__(16) char SM[22784];
  int t = threadIdx.x;

  if (blockIdx.x < NCHUNK) {
    // ---------------- p1: counting-sort edges into padded buckets ----------
    u32* keybuf = (u32*)SM;                                  // 16 KB
    unsigned char* bktbuf = (unsigned char*)(SM + 16384);    // 4 KB
    u32* hist = (u32*)(SM + 20480);
    u32* lstart = (u32*)(SM + 20992);
    u32* lofs = (u32*)(SM + 21504);
    u32* gb = (u32*)(SM + 22016);
    if (t < BK) hist[t] = 0;
    __syncthreads();
    int e0 = blockIdx.x * CHUNK;
    int n = min(CHUNK, EE - e0);
    for (int i = t; i < n; i += 256) {
      u32 d = (u32)col[e0 + i];
      atomicAdd(&hist[d >> 10], 1u);
    }
    __syncthreads();
    if (t == 0) {
      u32 s = 0;
      for (int b = 0; b < BK; b++) { lstart[b] = s; lofs[b] = s; s += hist[b]; }
    }
    __syncthreads();
    if (t < BK && hist[t]) gb[t] = (u32)t * CAP + atomicAdd(&gcur[t], hist[t]);
    __syncthreads();
    for (int i = t; i < n; i += 256) {
      u32 d = (u32)col[e0 + i];
      u32 s = (u32)row[e0 + i];
      u32 b = d >> 10;
      u32 p = atomicAdd(&lofs[b], 1u);
      keybuf[p] = ((d & 1023u) << 17) | s;
      bktbuf[p] = (unsigned char)b;
    }
    __syncthreads();
    for (int i = t; i < n; i += 256) {
      u32 b = bktbuf[i];
      binned[gb[b] + ((u32)i - lstart[b])] = keybuf[i];
    }
    return;
  }

  // ---------------- spec: spectral norm + Wt2, global-scratch matrices -----
  float* diag = (float*)SM;            // 128 f
  float* red = (float*)(SM + 512);     // 256 f
  float* uvec = (float*)(SM + 1536);   // 128 f
  int* jdx = (int*)(SM + 2048);        // 128 i
  float* itrS = (float*)(SM + 2560);
  int* jmS = (int*)(SM + 2564);
  int l = t & 63, w = t >> 6;
  int p = l & 15, q = l >> 4;

  // Wt2 fragment-permuted dump, direct from W:
  // Wt2[u32 u] = {W[k][c], W[k+1][c]}, c=n*16+(ll&15), k=ks*32+(ll>>4)*8+j
  for (int u = t; u < 16384; u += 256) {
    int h = u * 2;
    int n = h >> 12;
    int rem = h & 4095;
    int ks = rem >> 9;
    int rem2 = rem & 511;
    int ll = rem2 >> 3;
    int j = rem2 & 7;
    int c = n * 16 + (ll & 15);
    int k = ks * 32 + ((ll >> 4) << 3) + j;
    u32 lo = f2bf(W[k * NH + c]);
    u32 hi = f2bf(W[(k + 1) * NH + c]);
    ((u32*)Wt2)[u] = lo | (hi << 16);
  }
  // Wtg: bf16 Wt rows [c][k] (c-major, 256 bf16/row)
  for (int idx = t; idx < NF * NH; idx += 256) {
    int c = idx & 127, k = idx >> 7;
    Wtg[c * 256 + k] = f2bf(W[k * NH + c]);
  }
  __threadfence();
  __syncthreads();

  // gram via MFMA: frags straight from Wtg (global, L2-hot)
  f32x4 acc[2][8] = {};
#pragma unroll
  for (int ks = 0; ks < 8; ks++) {
    int kb = ks * 32 + q * 8;
    short8 afr[2], bfr[8];
#pragma unroll
    for (int m = 0; m < 2; m++) {
      int ra = w * 32 + m * 16 + p;
      afr[m] = *(const short8*)&Wtg[ra * 256 + kb];
    }
#pragma unroll
    for (int n = 0; n < 8; n++) {
      int r = n * 16 + p;
      bfr[n] = *(const short8*)&Wtg[r * 256 + kb];
    }
#pragma unroll
    for (int m = 0; m < 2; m++)
#pragma unroll
      for (int n = 0; n < 8; n++)
        acc[m][n] = __builtin_amdgcn_mfma_f32_16x16x32_bf16(afr[m], bfr[n], acc[m][n], 0, 0, 0);
  }
#pragma unroll
  for (int m = 0; m < 2; m++)
#pragma unroll
    for (int n = 0; n < 8; n++)
#pragma unroll
      for (int g = 0; g < 4; g++) {
        int r = w * 32 + m * 16 + q * 4 + g;
        int c = n * 16 + p;
        if (r == c) diag[r] = acc[m][n][g];
      }
  __syncthreads();
  if (t < 128) red[t] = diag[t];
  __syncthreads();
  for (int d = 64; d > 0; d >>= 1) { if (t < d) red[t] += red[t + d]; __syncthreads(); }
  if (t == 0) itrS[0] = 1.0f / red[0];
  __syncthreads();
  {
    float itr = itrS[0];
#pragma unroll
    for (int m = 0; m < 2; m++)
#pragma unroll
      for (int n = 0; n < 8; n++)
#pragma unroll
        for (int g = 0; g < 4; g++) {
          int r = w * 32 + m * 16 + q * 4 + g;
          int c = n * 16 + p;
          Mg0[r * 128 + c] = f2bf(acc[m][n][g] * itr);
        }
  }
  __threadfence();

  // 8 trace-normalized MFMA squarings (bf16, global ping-pong)
  u16* src = Mg0;
  u16* dst = Mg1;
  for (int s = 0; s < 8; s++) {
    __syncthreads();
    f32x4 mac[2][8] = {};
#pragma unroll
    for (int ks = 0; ks < 4; ks++) {
      int kb = ks * 32 + q * 8;
      short8 afr[2], bfr[8];
#pragma unroll
      for (int m = 0; m < 2; m++) {
        int ra = w * 32 + m * 16 + p;
        afr[m] = *(const short8*)&src[ra * 128 + kb];
      }
#pragma unroll
      for (int n = 0; n < 8; n++) {
        int r = n * 16 + p;
        bfr[n] = *(const short8*)&src[r * 128 + kb];
      }
#pragma unroll
      for (int m = 0; m < 2; m++)
#pragma unroll
        for (int n = 0; n < 8; n++)
          mac[m][n] = __builtin_amdgcn_mfma_f32_16x16x32_bf16(afr[m], bfr[n], mac[m][n], 0, 0, 0);
    }
#pragma unroll
    for (int m = 0; m < 2; m++)
#pragma unroll
      for (int n = 0; n < 8; n++)
#pragma unroll
        for (int g = 0; g < 4; g++) {
          int r = w * 32 + m * 16 + q * 4 + g;
          int c = n * 16 + p;
          if (r == c) diag[r] = mac[m][n][g];
        }
    __syncthreads();
    if (t < 128) red[t] = diag[t];
    __syncthreads();
    for (int d = 64; d > 0; d >>= 1) { if (t < d) red[t] += red[t + d]; __syncthreads(); }
    if (t == 0) itrS[0] = 1.0f / red[0];
    __syncthreads();
    float it2 = itrS[0];
#pragma unroll
    for (int m = 0; m < 2; m++)
#pragma unroll
      for (int n = 0; n < 8; n++)
#pragma unroll
        for (int g = 0; g < 4; g++) {
          int r = w * 32 + m * 16 + q * 4 + g;
          int c = n * 16 + p;
          dst[r * 128 + c] = f2bf(mac[m][n][g] * it2);
        }
    __threadfence();
    u16* tmp = src; src = dst; dst = tmp;
  }
  __syncthreads();

  // parallel argmax of diag -> u = row jm of M
  if (t < 128) { red[t] = diag[t]; jdx[t] = t; }
  __syncthreads();
  for (int d = 64; d > 0; d >>= 1) {
    if (t < d && red[t + d] > red[t]) { red[t] = red[t + d]; jdx[t] = jdx[t + d]; }
    __syncthreads();
  }
  if (t == 0) jmS[0] = jdx[0];
  __syncthreads();
  int jm = jmS[0];
  if (t < 128) uvec[t] = bf2f(src[jm * 128 + t]);
  __syncthreads();
  // Rayleigh on original W: lambda1 = |W u|^2 / |u|^2
  {
    float a2 = 0.f;
    const float* wr = &W[t * NH];
    for (int k = 0; k < NH; k++) a2 += wr[k] * uvec[k];
    red[t] = a2 * a2;
  }
  __syncthreads();
  for (int d = 128; d > 0; d >>= 1) { if (t < d) red[t] += red[t + d]; __syncthreads(); }
  if (t == 0) itrS[0] = red[0];
  __syncthreads();
  float num = itrS[0];
  if (t < 128) red[t] = uvec[t] * uvec[t];
  __syncthreads();
  for (int d = 64; d > 0; d >>= 1) { if (t < d) red[t] += red[t + d]; __syncthreads(); }
  if (t == 0) sig[0] = rsqrtf(num / red[0]);  // 1/sigma
}

// ---------------- P2: per-bucket counting sort in LDS (padded base) --------
__global__ __launch_bounds__(1024) void k_p2(const u32* __restrict__ binned,
                                             const u32* __restrict__ gcur,
                                             uint2* __restrict__ offdeg,
                                             float* __restrict__ dinv,
                                             int* __restrict__ csr) {
  __shared__ u32 hist[BNODE];
  __shared__ u32 loff[BNODE];
  __shared__ u32 cur[BNODE];
  __shared__ u32 stage[CAP];
  int b = blockIdx.x, t = threadIdx.x;
  u32 base = (u32)b * CAP;
  u32 cnt = gcur[b];
  hist[t] = 0;
  __syncthreads();
  for (u32 i = t; i < cnt; i += BNODE) {
    u32 key = binned[base + i];
    atomicAdd(&hist[key >> 17], 1u);
  }
  __syncthreads();
  u32 v = hist[t];
  loff[t] = v;
  __syncthreads();
  for (int d = 1; d < BNODE; d <<= 1) {
    u32 x = loff[t];
    u32 y = (t >= d) ? loff[t - d] : 0u;
    __syncthreads();
    loff[t] = x + y;
    __syncthreads();
  }
  u32 ex = loff[t] - v;
  cur[t] = ex;
  int g = b * BNODE + t;
  if (g < NN) {
    offdeg[g] = make_uint2(base + ex, base + ex + v);
    dinv[g] = rsqrtf((float)(v + 1u));
  }
  __syncthreads();
  if (cnt <= CAP) {
    for (u32 i = t; i < cnt; i += BNODE) {
      u32 key = binned[base + i];
      u32 p = atomicAdd(&cur[key >> 17], 1u);
      stage[p] = key & 0x1FFFFu;
    }
    __syncthreads();
    for (u32 i = t; i < cnt; i += BNODE) csr[base + i] = (int)stage[i];
  } else {
    for (u32 i = t; i < cnt; i += BNODE) {
      u32 key = binned[base + i];
      u32 p = atomicAdd(&cur[key >> 17], 1u);
      csr[base + p] = (int)(key & 0x1FFFFu);
    }
  }
}

// ------- MFMA GEMM (R17-exact): coalesced LDS-staged x, permuted Wt2 -------
__global__ __launch_bounds__(256) void k_mfma(const float* __restrict__ x,
                                              const u16* __restrict__ Wt2,
                                              const float* __restrict__ dinv,
                                              u16* __restrict__ hs) {
  __shared__ __align__(16) char LB[65536];
  int t = threadIdx.x;
  int l = t & 63, w = t >> 6;
  int row0 = blockIdx.x * 128;
  int lr = l & 15;
  int lk = (l >> 4) * 8;

  const float4* x4 = (const float4*)x;
#pragma unroll 8
  for (int i = t; i < 128 * 64; i += 256) {
    int r = i >> 6;
    int cq = i & 63;
    int gr = row0 + r;
    if (gr >= NN) gr = NN - 1;
    float4 v = x4[(size_t)gr * 64 + cq];
    uint2 wv;
    wv.x = (u32)f2bf(v.x) | ((u32)f2bf(v.y) << 16);
    wv.y = (u32)f2bf(v.z) | ((u32)f2bf(v.w) << 16);
    int kb = cq * 8;
    *(uint2*)(LB + r * 512 + (kb ^ ((r & 7) << 4))) = wv;
  }
  __syncthreads();

  int rbase = w * 32;
  f32x4 acc[2][8] = {};
#pragma unroll
  for (int ks = 0; ks < 8; ks++) {
    short8 bfr[8];
#pragma unroll
    for (int n = 0; n < 8; n++)
      bfr[n] = *(const short8*)&Wt2[(size_t)(((n * 8 + ks) * 64) + l) * 8];
    short8 afr[2];
#pragma unroll
    for (int m = 0; m < 2; m++) {
      int r = rbase + m * 16 + lr;
      int kb = (ks * 32 + lk) * 2;
      afr[m] = *(const short8*)(LB + r * 512 + (kb ^ ((r & 7) << 4)));
    }
#pragma unroll
    for (int m = 0; m < 2; m++)
#pragma unroll
      for (int n = 0; n < 8; n++)
        acc[m][n] = __builtin_amdgcn_mfma_f32_16x16x32_bf16(afr[m], bfr[n], acc[m][n], 0, 0, 0);
  }

  __syncthreads();
  u16* tile = (u16*)LB;
#pragma unroll
  for (int m = 0; m < 2; m++) {
    int rbl = w * 32 + m * 16 + (l >> 4) * 4;
    float dv[4];
#pragma unroll
    for (int g = 0; g < 4; g++) {
      int r = row0 + rbl + g;
      dv[g] = (r < NN) ? dinv[r] : 0.f;
    }
#pragma unroll
    for (int n = 0; n < 8; n++)
#pragma unroll
      for (int g = 0; g < 4; g++)
        tile[(rbl + g) * 128 + n * 16 + lr] = f2bf(acc[m][n][g] * dv[g]);
  }
  __syncthreads();
  const uint4* tl = (const uint4*)tile;
  size_t outb = (size_t)row0 * NH;
#pragma unroll
  for (int k = 0; k < 8; k++) {
    int u = t + k * 256;
    if (row0 + (u >> 4) < NN) *(uint4*)&hs[outb + (size_t)u * 8] = tl[u];
  }
}

// -------- gather: R14-exact (wave per node, 8-deep MLP unroll) -------------
__global__ __launch_bounds__(256) void k_gather(const u16* __restrict__ hs,
                                                const int* __restrict__ csr,
                                                const uint2* __restrict__ offdeg,
                                                const float* __restrict__ dinv,
                                                const float* __restrict__ b,
                                                const float* __restrict__ pa,
                                                const float* __restrict__ sig,
                                                float* __restrict__ out) {
  int wid = threadIdx.x >> 6;
  int lane = threadIdx.x & 63;
  int n = blockIdx.x * 4 + wid;
  if (n >= NN) return;
  uint2 od = offdeg[n];
  u32 s0 = od.x, s1 = od.y;
  const u32* hrow = (const u32*)hs;
  float ax, ay;
  {
    u32 u = hrow[(size_t)n * 64 + lane];  // self-loop term
    ax = bflo(u); ay = bfhi(u);
  }
  u32 e = s0;
  for (; e + 8 <= s1; e += 8) {
    int i0 = csr[e],     i1 = csr[e + 1], i2 = csr[e + 2], i3 = csr[e + 3];
    int i4 = csr[e + 4], i5 = csr[e + 5], i6 = csr[e + 6], i7 = csr[e + 7];
    u32 u0 = hrow[(size_t)i0 * 64 + lane];
    u32 u1 = hrow[(size_t)i1 * 64 + lane];
    u32 u2 = hrow[(size_t)i2 * 64 + lane];
    u32 u3 = hrow[(size_t)i3 * 64 + lane];
    u32 u4 = hrow[(size_t)i4 * 64 + lane];
    u32 u5 = hrow[(size_t)i5 * 64 + lane];
    u32 u6 = hrow[(size_t)i6 * 64 + lane];
    u32 u7 = hrow[(size_t)i7 * 64 + lane];
    ax += bflo(u0) + bflo(u1) + bflo(u2) + bflo(u3)
        + bflo(u4) + bflo(u5) + bflo(u6) + bflo(u7);
    ay += bfhi(u0) + bfhi(u1) + bfhi(u2) + bfhi(u3)
        + bfhi(u4) + bfhi(u5) + bfhi(u6) + bfhi(u7);
  }
  for (; e + 4 <= s1; e += 4) {
    int i0 = csr[e], i1 = csr[e + 1], i2 = csr[e + 2], i3 = csr[e + 3];
    u32 u0 = hrow[(size_t)i0 * 64 + lane];
    u32 u1 = hrow[(size_t)i1 * 64 + lane];
    u32 u2 = hrow[(size_t)i2 * 64 + lane];
    u32 u3 = hrow[(size_t)i3 * 64 + lane];
    ax += bflo(u0) + bflo(u1) + bflo(u2) + bflo(u3);
    ay += bfhi(u0) + bfhi(u1) + bfhi(u2) + bfhi(u3);
  }
  for (; e < s1; e++) {
    u32 u = hrow[(size_t)csr[e] * 64 + lane];
    ax += bflo(u); ay += bfhi(u);
  }
  float dv = dinv[n] * sig[0];
  float2 bb = *(const float2*)&b[lane * 2];
  float a = pa[0];
  float v0 = ax * dv + bb.x;
  float v1 = ay * dv + bb.y;
  float2 o;
  o.x = v0 > 0.f ? v0 : a * v0;
  o.y = v1 > 0.f ? v1 : a * v1;
  *(float2*)&out[(size_t)n * NH + lane * 2] = o;
}

// ---------------- launch ----------------
extern "C" void kernel_launch(void* const* d_in, const int* in_sizes, int n_in,
                              void* d_out, int out_size, void* d_ws, size_t ws_size,
                              hipStream_t stream) {
  const float* x = (const float*)d_in[0];
  const int* ei = (const int*)d_in[1];
  const float* W = (const float*)d_in[2];
  const float* b = (const float*)d_in[3];
  const float* pa = (const float*)d_in[4];
  float* out = (float*)d_out;
  const int* row = ei;
  const int* col = ei + EE;

  char* base = (char*)d_ws;
  size_t o = 0;
  auto alloc = [&](size_t bytes) -> void* {
    void* p = base + o;
    o += (bytes + 63) & ~(size_t)63;
    return p;
  };
  u32* gcur = (u32*)alloc(BK * 4);
  float* sig = (float*)alloc(64);
  float* dinv = (float*)alloc((size_t)NN * 4);
  uint2* offdeg = (uint2*)alloc((size_t)NN * 8);
  u32* binned = (u32*)alloc((size_t)BK * CAP * 4);
  int* csr = (int*)alloc((size_t)BK * CAP * 4);
  u16* Wt2 = (u16*)alloc((size_t)NF * NH * 2);
  u16* Wtg = (u16*)alloc((size_t)NF * NH * 2);
  u16* Mg0 = (u16*)alloc((size_t)NH * NH * 2);
  u16* Mg1 = (u16*)alloc((size_t)NH * NH * 2);
  u16* hs = (u16*)alloc((size_t)NN * NH * 2);
  (void)ws_size; (void)in_sizes; (void)n_in; (void)out_size;

  hipMemsetAsync(gcur, 0, BK * 4, stream);
  k_p1s<<<NCHUNK + 1, 256, 0, stream>>>(row, col, gcur, binned, W, Wt2, Wtg,
                                        Mg0, Mg1, sig);
  k_p2<<<BK, BNODE, 0, stream>>>(binned, gcur, offdeg, dinv, csr);
  k_mfma<<<(NN + 127) / 128, 256, 0, stream>>>(x, Wt2, dinv, hs);
  k_gather<<<(NN + 3) / 4, 256, 0, stream>>>(hs, csr, offdeg, dinv, b, pa, sig, out);
}

// Round 20
// 183.988 us; speedup vs baseline: 1.3430x; 1.3060x over previous
//
#include <hip/hip_runtime.h>

#define NN 100000
#define EE 1600000
#define NF 256
#define NH 128

#define BK 98        // buckets of 1024 nodes
#define BNODE 1024
#define CHUNK 4096
#define NCHUNK ((EE + CHUNK - 1) / CHUNK)  // 391
#define CAP 24576    // per-bucket capacity (counts ~16327±128; huge margin)

typedef unsigned int u32;
typedef unsigned short u16;
typedef __attribute__((ext_vector_type(8))) short short8;
typedef __attribute__((ext_vector_type(4))) float f32x4;

static __device__ __forceinline__ u16 f2bf(float f) {
  u32 u = __float_as_uint(f);
  u32 r = (u + 0x7FFFu + ((u >> 16) & 1u)) >> 16;
  return (u16)r;
}
static __device__ __forceinline__ float bflo(u32 u) { return __uint_as_float(u << 16); }
static __device__ __forceinline__ float bfhi(u32 u) { return __uint_as_float(u & 0xFFFF0000u); }

// ============ k_p1s: blocks 0..390 = edge binning; block 391 = spectral ====
// R17-exact: spec branch keeps its matrices in LDS (69KB static). p1's grid
// is only 391 blocks (<=2/CU from grid shape), so the large LDS costs p1
// nothing; no launch_bounds cap (R18/R19's caps spilled the spec branch).
__global__ __launch_bounds__(256) void k_p1s(const int* __restrict__ row,
                                             const int* __restrict__ col,
                                             u32* __restrict__ gcur,
                                             u32* __restrict__ binned,
                                             const float* __restrict__ W,
                                             u16* __restrict__ Wt2,
                                             float* __restrict__ sig) {
  __shared__ __align__(16) char SM[69632];
  int t = threadIdx.x;

  if (blockIdx.x < NCHUNK) {
    // ---------------- p1: counting-sort edges into padded buckets ----------
    u32* keybuf = (u32*)SM;                                  // 16 KB
    unsigned char* bktbuf = (unsigned char*)(SM + 16384);    // 4 KB
    u32* hist = (u32*)(SM + 20480);
    u32* lstart = (u32*)(SM + 20992);
    u32* lofs = (u32*)(SM + 21504);
    u32* gb = (u32*)(SM + 22016);
    if (t < BK) hist[t] = 0;
    __syncthreads();
    int e0 = blockIdx.x * CHUNK;
    int n = min(CHUNK, EE - e0);
    for (int i = t; i < n; i += 256) {
      u32 d = (u32)col[e0 + i];
      atomicAdd(&hist[d >> 10], 1u);
    }
    __syncthreads();
    if (t == 0) {
      u32 s = 0;
      for (int b = 0; b < BK; b++) { lstart[b] = s; lofs[b] = s; s += hist[b]; }
    }
    __syncthreads();
    if (t < BK && hist[t]) gb[t] = (u32)t * CAP + atomicAdd(&gcur[t], hist[t]);
    __syncthreads();
    for (int i = t; i < n; i += 256) {
      u32 d = (u32)col[e0 + i];
      u32 s = (u32)row[e0 + i];
      u32 b = d >> 10;
      u32 p = atomicAdd(&lofs[b], 1u);
      keybuf[p] = ((d & 1023u) << 17) | s;
      bktbuf[p] = (unsigned char)b;
    }
    __syncthreads();
    for (int i = t; i < n; i += 256) {
      u32 b = bktbuf[i];
      binned[gb[b] + ((u32)i - lstart[b])] = keybuf[i];
    }
    return;
  }

  // ---------------- spec: spectral norm + fragment-permuted Wt2 ------------
  char* MB = SM;                          // 64 KB work matrix
  float* diag = (float*)(SM + 65536);     // 128 f
  float* red = (float*)(SM + 66048);      // 256 f
  float* uvec = (float*)(SM + 67072);     // 128 f
  int* jdx = (int*)(SM + 67584);          // 128 i
  float* itrS = (float*)(SM + 68096);
  int* jmS = (int*)(SM + 68100);
  int l = t & 63, w = t >> 6;
  int p = l & 15, q = l >> 4;

  // stage Wt bf16 into LDS (512B rows, XOR-swizzled)
  for (int base = t * 4; base < NF * NH; base += 1024) {
    float4 v = *(const float4*)&W[base];
    int k = base >> 7, c0 = base & 127;
#pragma unroll
    for (int i = 0; i < 4; i++) {
      int c = c0 + i;
      int inner = (k * 2) ^ ((c & 7) << 4);
      *(u16*)(MB + c * 512 + inner) = f2bf(((const float*)&v)[i]);
    }
  }
  __syncthreads();
  // dump Wt2 in fragment-permuted order:
  // Wt2[(((n*8+ks)*64)+l)*8+j] = Wt[c][k], c=n*16+(l&15), k=ks*32+(l>>4)*8+j
  for (int u = t; u < 16384; u += 256) {
    int h = u * 2;
    int n = h >> 12;
    int rem = h & 4095;
    int ks = rem >> 9;
    int rem2 = rem & 511;
    int ll = rem2 >> 3;
    int j = rem2 & 7;
    int c = n * 16 + (ll & 15);
    int k = ks * 32 + ((ll >> 4) << 3) + j;
    ((u32*)Wt2)[u] = *(u32*)(MB + c * 512 + ((2 * k) ^ ((c & 7) << 4)));
  }

  // gram via MFMA
  f32x4 acc[2][8] = {};
#pragma unroll
  for (int ks = 0; ks < 8; ks++) {
    int kb = (ks * 32 + q * 8) * 2;
    short8 afr[2], bfr[8];
#pragma unroll
    for (int m = 0; m < 2; m++) {
      int ra = w * 32 + m * 16 + p;
      afr[m] = *(const short8*)(MB + ra * 512 + (kb ^ ((ra & 7) << 4)));
    }
#pragma unroll
    for (int n = 0; n < 8; n++) {
      int r = n * 16 + p;
      bfr[n] = *(const short8*)(MB + r * 512 + (kb ^ ((r & 7) << 4)));
    }
#pragma unroll
    for (int m = 0; m < 2; m++)
#pragma unroll
      for (int n = 0; n < 8; n++)
        acc[m][n] = __builtin_amdgcn_mfma_f32_16x16x32_bf16(afr[m], bfr[n], acc[m][n], 0, 0, 0);
  }
#pragma unroll
  for (int m = 0; m < 2; m++)
#pragma unroll
    for (int n = 0; n < 8; n++)
#pragma unroll
      for (int g = 0; g < 4; g++) {
        int r = w * 32 + m * 16 + q * 4 + g;
        int c = n * 16 + p;
        if (r == c) diag[r] = acc[m][n][g];
      }
  __syncthreads();
  if (t < 128) red[t] = diag[t];
  __syncthreads();
  for (int d = 64; d > 0; d >>= 1) { if (t < d) red[t] += red[t + d]; __syncthreads(); }
  if (t == 0) itrS[0] = 1.0f / red[0];
  __syncthreads();
  {
    float itr = itrS[0];
#pragma unroll
    for (int m = 0; m < 2; m++)
#pragma unroll
      for (int n = 0; n < 8; n++)
#pragma unroll
        for (int g = 0; g < 4; g++) {
          int r = w * 32 + m * 16 + q * 4 + g;
          int c = n * 16 + p;
          *(u16*)(MB + r * 256 + ((c * 2) ^ ((r & 7) << 4))) = f2bf(acc[m][n][g] * itr);
        }
  }

  // 8 trace-normalized MFMA squarings (bf16, in LDS)
  char* src = MB;
  char* dst = MB + 32768;
  for (int s = 0; s < 8; s++) {
    __syncthreads();
    f32x4 mac[2][8] = {};
#pragma unroll
    for (int ks = 0; ks < 4; ks++) {
      int kb = (ks * 32 + q * 8) * 2;
      short8 afr[2], bfr[8];
#pragma unroll
      for (int m = 0; m < 2; m++) {
        int ra = w * 32 + m * 16 + p;
        afr[m] = *(const short8*)(src + ra * 256 + (kb ^ ((ra & 7) << 4)));
      }
#pragma unroll
      for (int n = 0; n < 8; n++) {
        int r = n * 16 + p;
        bfr[n] = *(const short8*)(src + r * 256 + (kb ^ ((r & 7) << 4)));
      }
#pragma unroll
      for (int m = 0; m < 2; m++)
#pragma unroll
        for (int n = 0; n < 8; n++)
          mac[m][n] = __builtin_amdgcn_mfma_f32_16x16x32_bf16(afr[m], bfr[n], mac[m][n], 0, 0, 0);
    }
#pragma unroll
    for (int m = 0; m < 2; m++)
#pragma unroll
      for (int n = 0; n < 8; n++)
#pragma unroll
        for (int g = 0; g < 4; g++) {
          int r = w * 32 + m * 16 + q * 4 + g;
          int c = n * 16 + p;
          if (r == c) diag[r] = mac[m][n][g];
        }
    __syncthreads();
    if (t < 128) red[t] = diag[t];
    __syncthreads();
    for (int d = 64; d > 0; d >>= 1) { if (t < d) red[t] += red[t + d]; __syncthreads(); }
    if (t == 0) itrS[0] = 1.0f / red[0];
    __syncthreads();
    float it2 = itrS[0];
#pragma unroll
    for (int m = 0; m < 2; m++)
#pragma unroll
      for (int n = 0; n < 8; n++)
#pragma unroll
        for (int g = 0; g < 4; g++) {
          int r = w * 32 + m * 16 + q * 4 + g;
          int c = n * 16 + p;
          *(u16*)(dst + r * 256 + ((c * 2) ^ ((r & 7) << 4))) = f2bf(mac[m][n][g] * it2);
        }
    char* tmp = src; src = dst; dst = tmp;
  }
  __syncthreads();

  // parallel argmax of diag
  if (t < 128) { red[t] = diag[t]; jdx[t] = t; }
  __syncthreads();
  for (int d = 64; d > 0; d >>= 1) {
    if (t < d && red[t + d] > red[t]) { red[t] = red[t + d]; jdx[t] = jdx[t + d]; }
    __syncthreads();
  }
  if (t == 0) jmS[0] = jdx[0];
  __syncthreads();
  int jm = jmS[0];
  if (t < 128) {
    u16 hv = *(u16*)(src + jm * 256 + ((t * 2) ^ ((jm & 7) << 4)));
    uvec[t] = __uint_as_float(((u32)hv) << 16);
  }
  __syncthreads();
  // Rayleigh on original W: lambda1 = |W u|^2 / |u|^2
  {
    float a2 = 0.f;
    const float* wr = &W[t * NH];
    for (int k = 0; k < NH; k++) a2 += wr[k] * uvec[k];
    red[t] = a2 * a2;
  }
  __syncthreads();
  for (int d = 128; d > 0; d >>= 1) { if (t < d) red[t] += red[t + d]; __syncthreads(); }
  if (t == 0) itrS[0] = red[0];  // numerator
  __syncthreads();
  float num = itrS[0];
  if (t < 128) red[t] = uvec[t] * uvec[t];
  __syncthreads();
  for (int d = 64; d > 0; d >>= 1) { if (t < d) red[t] += red[t + d]; __syncthreads(); }
  if (t == 0) sig[0] = rsqrtf(num / red[0]);  // 1/sigma
}

// ---------------- P2: per-bucket counting sort in LDS (padded base) --------
__global__ __launch_bounds__(1024) void k_p2(const u32* __restrict__ binned,
                                             const u32* __restrict__ gcur,
                                             uint2* __restrict__ offdeg,
                                             float* __restrict__ dinv,
                                             int* __restrict__ csr) {
  __shared__ u32 hist[BNODE];
  __shared__ u32 loff[BNODE];
  __shared__ u32 cur[BNODE];
  __shared__ u32 stage[CAP];
  int b = blockIdx.x, t = threadIdx.x;
  u32 base = (u32)b * CAP;
  u32 cnt = gcur[b];
  hist[t] = 0;
  __syncthreads();
  for (u32 i = t; i < cnt; i += BNODE) {
    u32 key = binned[base + i];
    atomicAdd(&hist[key >> 17], 1u);
  }
  __syncthreads();
  u32 v = hist[t];
  loff[t] = v;
  __syncthreads();
  for (int d = 1; d < BNODE; d <<= 1) {
    u32 x = loff[t];
    u32 y = (t >= d) ? loff[t - d] : 0u;
    __syncthreads();
    loff[t] = x + y;
    __syncthreads();
  }
  u32 ex = loff[t] - v;
  cur[t] = ex;
  int g = b * BNODE + t;
  if (g < NN) {
    offdeg[g] = make_uint2(base + ex, base + ex + v);
    dinv[g] = rsqrtf((float)(v + 1u));
  }
  __syncthreads();
  if (cnt <= CAP) {
    for (u32 i = t; i < cnt; i += BNODE) {
      u32 key = binned[base + i];
      u32 p = atomicAdd(&cur[key >> 17], 1u);
      stage[p] = key & 0x1FFFFu;
    }
    __syncthreads();
    for (u32 i = t; i < cnt; i += BNODE) csr[base + i] = (int)stage[i];
  } else {
    for (u32 i = t; i < cnt; i += BNODE) {
      u32 key = binned[base + i];
      u32 p = atomicAdd(&cur[key >> 17], 1u);
      csr[base + p] = (int)(key & 0x1FFFFu);
    }
  }
}

// ------- MFMA GEMM (R17-exact): coalesced LDS-staged x, permuted Wt2 -------
__global__ __launch_bounds__(256) void k_mfma(const float* __restrict__ x,
                                              const u16* __restrict__ Wt2,
                                              const float* __restrict__ dinv,
                                              u16* __restrict__ hs) {
  __shared__ __align__(16) char LB[65536];
  int t = threadIdx.x;
  int l = t & 63, w = t >> 6;
  int row0 = blockIdx.x * 128;
  int lr = l & 15;
  int lk = (l >> 4) * 8;

  const float4* x4 = (const float4*)x;
#pragma unroll 8
  for (int i = t; i < 128 * 64; i += 256) {
    int r = i >> 6;
    int cq = i & 63;
    int gr = row0 + r;
    if (gr >= NN) gr = NN - 1;
    float4 v = x4[(size_t)gr * 64 + cq];
    uint2 wv;
    wv.x = (u32)f2bf(v.x) | ((u32)f2bf(v.y) << 16);
    wv.y = (u32)f2bf(v.z) | ((u32)f2bf(v.w) << 16);
    int kb = cq * 8;
    *(uint2*)(LB + r * 512 + (kb ^ ((r & 7) << 4))) = wv;
  }
  __syncthreads();

  int rbase = w * 32;
  f32x4 acc[2][8] = {};
#pragma unroll
  for (int ks = 0; ks < 8; ks++) {
    short8 bfr[8];
#pragma unroll
    for (int n = 0; n < 8; n++)
      bfr[n] = *(const short8*)&Wt2[(size_t)(((n * 8 + ks) * 64) + l) * 8];
    short8 afr[2];
#pragma unroll
    for (int m = 0; m < 2; m++) {
      int r = rbase + m * 16 + lr;
      int kb = (ks * 32 + lk) * 2;
      afr[m] = *(const short8*)(LB + r * 512 + (kb ^ ((r & 7) << 4)));
    }
#pragma unroll
    for (int m = 0; m < 2; m++)
#pragma unroll
      for (int n = 0; n < 8; n++)
        acc[m][n] = __builtin_amdgcn_mfma_f32_16x16x32_bf16(afr[m], bfr[n], acc[m][n], 0, 0, 0);
  }

  __syncthreads();
  u16* tile = (u16*)LB;
#pragma unroll
  for (int m = 0; m < 2; m++) {
    int rbl = w * 32 + m * 16 + (l >> 4) * 4;
    float dv[4];
#pragma unroll
    for (int g = 0; g < 4; g++) {
      int r = row0 + rbl + g;
      dv[g] = (r < NN) ? dinv[r] : 0.f;
    }
#pragma unroll
    for (int n = 0; n < 8; n++)
#pragma unroll
      for (int g = 0; g < 4; g++)
        tile[(rbl + g) * 128 + n * 16 + lr] = f2bf(acc[m][n][g] * dv[g]);
  }
  __syncthreads();
  const uint4* tl = (const uint4*)tile;
  size_t outb = (size_t)row0 * NH;
#pragma unroll
  for (int k = 0; k < 8; k++) {
    int u = t + k * 256;
    if (row0 + (u >> 4) < NN) *(uint4*)&hs[outb + (size_t)u * 8] = tl[u];
  }
}

// -------- gather: wave per node, 16-deep MLP head (mean degree = 16) -------
__global__ __launch_bounds__(256) void k_gather(const u16* __restrict__ hs,
                                                const int* __restrict__ csr,
                                                const uint2* __restrict__ offdeg,
                                                const float* __restrict__ dinv,
                                                const float* __restrict__ b,
                                                const float* __restrict__ pa,
                                                const float* __restrict__ sig,
                                                float* __restrict__ out) {
  int wid = threadIdx.x >> 6;
  int lane = threadIdx.x & 63;
  int n = blockIdx.x * 4 + wid;
  if (n >= NN) return;
  uint2 od = offdeg[n];
  u32 s0 = od.x, s1 = od.y;
  const u32* hrow = (const u32*)hs;
  float ax, ay;
  {
    u32 u = hrow[(size_t)n * 64 + lane];  // self-loop term
    ax = bflo(u); ay = bfhi(u);
  }
  u32 e = s0;
  for (; e + 16 <= s1; e += 16) {
    int ii[16];
#pragma unroll
    for (int j = 0; j < 16; j++) ii[j] = csr[e + j];
    u32 uu[16];
#pragma unroll
    for (int j = 0; j < 16; j++) uu[j] = hrow[(size_t)ii[j] * 64 + lane];
#pragma unroll
    for (int j = 0; j < 16; j++) { ax += bflo(uu[j]); ay += bfhi(uu[j]); }
  }
  for (; e + 8 <= s1; e += 8) {
    int i0 = csr[e],     i1 = csr[e + 1], i2 = csr[e + 2], i3 = csr[e + 3];
    int i4 = csr[e + 4], i5 = csr[e + 5], i6 = csr[e + 6], i7 = csr[e + 7];
    u32 u0 = hrow[(size_t)i0 * 64 + lane];
    u32 u1 = hrow[(size_t)i1 * 64 + lane];
    u32 u2 = hrow[(size_t)i2 * 64 + lane];
    u32 u3 = hrow[(size_t)i3 * 64 + lane];
    u32 u4 = hrow[(size_t)i4 * 64 + lane];
    u32 u5 = hrow[(size_t)i5 * 64 + lane];
    u32 u6 = hrow[(size_t)i6 * 64 + lane];
    u32 u7 = hrow[(size_t)i7 * 64 + lane];
    ax += bflo(u0) + bflo(u1) + bflo(u2) + bflo(u3)
        + bflo(u4) + bflo(u5) + bflo(u6) + bflo(u7);
    ay += bfhi(u0) + bfhi(u1) + bfhi(u2) + bfhi(u3)
        + bfhi(u4) + bfhi(u5) + bfhi(u6) + bfhi(u7);
  }
  for (; e + 4 <= s1; e += 4) {
    int i0 = csr[e], i1 = csr[e + 1], i2 = csr[e + 2], i3 = csr[e + 3];
    u32 u0 = hrow[(size_t)i0 * 64 + lane];
    u32 u1 = hrow[(size_t)i1 * 64 + lane];
    u32 u2 = hrow[(size_t)i2 * 64 + lane];
    u32 u3 = hrow[(size_t)i3 * 64 + lane];
    ax += bflo(u0) + bflo(u1) + bflo(u2) + bflo(u3);
    ay += bfhi(u0) + bfhi(u1) + bfhi(u2) + bfhi(u3);
  }
  for (; e < s1; e++) {
    u32 u = hrow[(size_t)csr[e] * 64 + lane];
    ax += bflo(u); ay += bfhi(u);
  }
  float dv = dinv[n] * sig[0];
  float2 bb = *(const float2*)&b[lane * 2];
  float a = pa[0];
  float v0 = ax * dv + bb.x;
  float v1 = ay * dv + bb.y;
  float2 o;
  o.x = v0 > 0.f ? v0 : a * v0;
  o.y = v1 > 0.f ? v1 : a * v1;
  *(float2*)&out[(size_t)n * NH + lane * 2] = o;
}

// ---------------- launch ----------------
extern "C" void kernel_launch(void* const* d_in, const int* in_sizes, int n_in,
                              void* d_out, int out_size, void* d_ws, size_t ws_size,
                              hipStream_t stream) {
  const float* x = (const float*)d_in[0];
  const int* ei = (const int*)d_in[1];
  const float* W = (const float*)d_in[2];
  const float* b = (const float*)d_in[3];
  const float* pa = (const float*)d_in[4];
  float* out = (float*)d_out;
  const int* row = ei;
  const int* col = ei + EE;

  char* base = (char*)d_ws;
  size_t o = 0;
  auto alloc = [&](size_t bytes) -> void* {
    void* p = base + o;
    o += (bytes + 63) & ~(size_t)63;
    return p;
  };
  u32* gcur = (u32*)alloc(BK * 4);
  float* sig = (float*)alloc(64);
  float* dinv = (float*)alloc((size_t)NN * 4);
  uint2* offdeg = (uint2*)alloc((size_t)NN * 8);
  u32* binned = (u32*)alloc((size_t)BK * CAP * 4);
  int* csr = (int*)alloc((size_t)BK * CAP * 4);
  u16* Wt2 = (u16*)alloc((size_t)NF * NH * 2);
  u16* hs = (u16*)alloc((size_t)NN * NH * 2);
  (void)ws_size; (void)in_sizes; (void)n_in; (void)out_size;

  hipMemsetAsync(gcur, 0, BK * 4, stream);
  k_p1s<<<NCHUNK + 1, 256, 0, stream>>>(row, col, gcur, binned, W, Wt2, sig);
  k_p2<<<BK, BNODE, 0, stream>>>(binned, gcur, offdeg, dinv, csr);
  k_mfma<<<(NN + 127) / 128, 256, 0, stream>>>(x, Wt2, dinv, hs);
  k_gather<<<(NN + 3) / 4, 256, 0, stream>>>(hs, csr, offdeg, dinv, b, pa, sig, out);
}

// Round 21
// 178.039 us; speedup vs baseline: 1.3878x; 1.0334x over previous
//
#include <hip/hip_runtime.h>

#define NN 100000
#define EE 1600000
#define NF 256
#define NH 128

#define BK 98        // buckets of 1024 nodes
#define BNODE 1024
#define CHUNK 4096
#define NCHUNK ((EE + CHUNK - 1) / CHUNK)  // 391
#define CAP 24576    // per-bucket capacity (counts ~16327±128; huge margin)

typedef unsigned int u32;
typedef unsigned short u16;
typedef __attribute__((ext_vector_type(8))) short short8;
typedef __attribute__((ext_vector_type(4))) float f32x4;

static __device__ __forceinline__ u16 f2bf(float f) {
  u32 u = __float_as_uint(f);
  u32 r = (u + 0x7FFFu + ((u >> 16) & 1u)) >> 16;
  return (u16)r;
}
static __device__ __forceinline__ float bflo(u32 u) { return __uint_as_float(u << 16); }
static __device__ __forceinline__ float bfhi(u32 u) { return __uint_as_float(u & 0xFFFF0000u); }

// ============ k_p1s: blocks 0..390 = edge binning; block 391 = spectral ====
// R17-exact structure (no launch_bounds cap: R18/R19's caps spilled spec).
__global__ __launch_bounds__(256) void k_p1s(const int* __restrict__ row,
                                             const int* __restrict__ col,
                                             u32* __restrict__ gcur,
                                             u32* __restrict__ binned,
                                             const float* __restrict__ W,
                                             u16* __restrict__ Wt2,
                                             float* __restrict__ sig) {
  __shared__ __align__(16) char SM[69632];
  int t = threadIdx.x;

  if (blockIdx.x < NCHUNK) {
    // ---------------- p1: counting-sort edges into padded buckets ----------
    u32* keybuf = (u32*)SM;                                  // 16 KB
    unsigned char* bktbuf = (unsigned char*)(SM + 16384);    // 4 KB
    u32* hist = (u32*)(SM + 20480);
    u32* lstart = (u32*)(SM + 20992);
    u32* lofs = (u32*)(SM + 21504);
    u32* gb = (u32*)(SM + 22016);
    if (t < BK) hist[t] = 0;
    __syncthreads();
    int e0 = blockIdx.x * CHUNK;
    int n = min(CHUNK, EE - e0);
    for (int i = t; i < n; i += 256) {
      u32 d = (u32)col[e0 + i];
      atomicAdd(&hist[d >> 10], 1u);
    }
    __syncthreads();
    if (t == 0) {
      u32 s = 0;
      for (int b = 0; b < BK; b++) { lstart[b] = s; lofs[b] = s; s += hist[b]; }
    }
    __syncthreads();
    if (t < BK && hist[t]) gb[t] = (u32)t * CAP + atomicAdd(&gcur[t], hist[t]);
    __syncthreads();
    for (int i = t; i < n; i += 256) {
      u32 d = (u32)col[e0 + i];
      u32 s = (u32)row[e0 + i];
      u32 b = d >> 10;
      u32 p = atomicAdd(&lofs[b], 1u);
      keybuf[p] = ((d & 1023u) << 17) | s;
      bktbuf[p] = (unsigned char)b;
    }
    __syncthreads();
    for (int i = t; i < n; i += 256) {
      u32 b = bktbuf[i];
      binned[gb[b] + ((u32)i - lstart[b])] = keybuf[i];
    }
    return;
  }

  // ---------------- spec: spectral norm + fragment-permuted Wt2 ------------
  char* MB = SM;                          // 64 KB work matrix
  float* diag = (float*)(SM + 65536);     // 128 f
  float* red = (float*)(SM + 66048);      // 256 f
  float* uvec = (float*)(SM + 67072);     // 128 f
  int* jdx = (int*)(SM + 67584);          // 128 i
  float* itrS = (float*)(SM + 68096);
  int* jmS = (int*)(SM + 68100);
  int l = t & 63, w = t >> 6;
  int p = l & 15, q = l >> 4;

  // stage Wt bf16 into LDS (512B rows, XOR-swizzled)
  for (int base = t * 4; base < NF * NH; base += 1024) {
    float4 v = *(const float4*)&W[base];
    int k = base >> 7, c0 = base & 127;
#pragma unroll
    for (int i = 0; i < 4; i++) {
      int c = c0 + i;
      int inner = (k * 2) ^ ((c & 7) << 4);
      *(u16*)(MB + c * 512 + inner) = f2bf(((const float*)&v)[i]);
    }
  }
  __syncthreads();
  // dump Wt2 in fragment-permuted order:
  // Wt2[(((n*8+ks)*64)+l)*8+j] = Wt[c][k], c=n*16+(l&15), k=ks*32+(l>>4)*8+j
  for (int u = t; u < 16384; u += 256) {
    int h = u * 2;
    int n = h >> 12;
    int rem = h & 4095;
    int ks = rem >> 9;
    int rem2 = rem & 511;
    int ll = rem2 >> 3;
    int j = rem2 & 7;
    int c = n * 16 + (ll & 15);
    int k = ks * 32 + ((ll >> 4) << 3) + j;
    ((u32*)Wt2)[u] = *(u32*)(MB + c * 512 + ((2 * k) ^ ((c & 7) << 4)));
  }

  // gram via MFMA
  f32x4 acc[2][8] = {};
#pragma unroll
  for (int ks = 0; ks < 8; ks++) {
    int kb = (ks * 32 + q * 8) * 2;
    short8 afr[2], bfr[8];
#pragma unroll
    for (int m = 0; m < 2; m++) {
      int ra = w * 32 + m * 16 + p;
      afr[m] = *(const short8*)(MB + ra * 512 + (kb ^ ((ra & 7) << 4)));
    }
#pragma unroll
    for (int n = 0; n < 8; n++) {
      int r = n * 16 + p;
      bfr[n] = *(const short8*)(MB + r * 512 + (kb ^ ((r & 7) << 4)));
    }
#pragma unroll
    for (int m = 0; m < 2; m++)
#pragma unroll
      for (int n = 0; n < 8; n++)
        acc[m][n] = __builtin_amdgcn_mfma_f32_16x16x32_bf16(afr[m], bfr[n], acc[m][n], 0, 0, 0);
  }
#pragma unroll
  for (int m = 0; m < 2; m++)
#pragma unroll
    for (int n = 0; n < 8; n++)
#pragma unroll
      for (int g = 0; g < 4; g++) {
        int r = w * 32 + m * 16 + q * 4 + g;
        int c = n * 16 + p;
        if (r == c) diag[r] = acc[m][n][g];
      }
  __syncthreads();
  if (t < 128) red[t] = diag[t];
  __syncthreads();
  for (int d = 64; d > 0; d >>= 1) { if (t < d) red[t] += red[t + d]; __syncthreads(); }
  if (t == 0) itrS[0] = 1.0f / red[0];
  __syncthreads();
  {
    float itr = itrS[0];
#pragma unroll
    for (int m = 0; m < 2; m++)
#pragma unroll
      for (int n = 0; n < 8; n++)
#pragma unroll
        for (int g = 0; g < 4; g++) {
          int r = w * 32 + m * 16 + q * 4 + g;
          int c = n * 16 + p;
          *(u16*)(MB + r * 256 + ((c * 2) ^ ((r & 7) << 4))) = f2bf(acc[m][n][g] * itr);
        }
  }

  // 8 trace-normalized MFMA squarings (bf16, in LDS)
  char* src = MB;
  char* dst = MB + 32768;
  for (int s = 0; s < 8; s++) {
    __syncthreads();
    f32x4 mac[2][8] = {};
#pragma unroll
    for (int ks = 0; ks < 4; ks++) {
      int kb = (ks * 32 + q * 8) * 2;
      short8 afr[2], bfr[8];
#pragma unroll
      for (int m = 0; m < 2; m++) {
        int ra = w * 32 + m * 16 + p;
        afr[m] = *(const short8*)(src + ra * 256 + (kb ^ ((ra & 7) << 4)));
      }
#pragma unroll
      for (int n = 0; n < 8; n++) {
        int r = n * 16 + p;
        bfr[n] = *(const short8*)(src + r * 256 + (kb ^ ((r & 7) << 4)));
      }
#pragma unroll
      for (int m = 0; m < 2; m++)
#pragma unroll
        for (int n = 0; n < 8; n++)
          mac[m][n] = __builtin_amdgcn_mfma_f32_16x16x32_bf16(afr[m], bfr[n], mac[m][n], 0, 0, 0);
    }
#pragma unroll
    for (int m = 0; m < 2; m++)
#pragma unroll
      for (int n = 0; n < 8; n++)
#pragma unroll
        for (int g = 0; g < 4; g++) {
          int r = w * 32 + m * 16 + q * 4 + g;
          int c = n * 16 + p;
          if (r == c) diag[r] = mac[m][n][g];
        }
    __syncthreads();
    if (t < 128) red[t] = diag[t];
    __syncthreads();
    for (int d = 64; d > 0; d >>= 1) { if (t < d) red[t] += red[t + d]; __syncthreads(); }
    if (t == 0) itrS[0] = 1.0f / red[0];
    __syncthreads();
    float it2 = itrS[0];
#pragma unroll
    for (int m = 0; m < 2; m++)
#pragma unroll
      for (int n = 0; n < 8; n++)
#pragma unroll
        for (int g = 0; g < 4; g++) {
          int r = w * 32 + m * 16 + q * 4 + g;
          int c = n * 16 + p;
          *(u16*)(dst + r * 256 + ((c * 2) ^ ((r & 7) << 4))) = f2bf(mac[m][n][g] * it2);
        }
    char* tmp = src; src = dst; dst = tmp;
  }
  __syncthreads();

  // parallel argmax of diag
  if (t < 128) { red[t] = diag[t]; jdx[t] = t; }
  __syncthreads();
  for (int d = 64; d > 0; d >>= 1) {
    if (t < d && red[t + d] > red[t]) { red[t] = red[t + d]; jdx[t] = jdx[t + d]; }
    __syncthreads();
  }
  if (t == 0) jmS[0] = jdx[0];
  __syncthreads();
  int jm = jmS[0];
  if (t < 128) {
    u16 hv = *(u16*)(src + jm * 256 + ((t * 2) ^ ((jm & 7) << 4)));
    uvec[t] = __uint_as_float(((u32)hv) << 16);
  }
  __syncthreads();
  // Rayleigh on original W: lambda1 = |W u|^2 / |u|^2
  {
    float a2 = 0.f;
    const float* wr = &W[t * NH];
    for (int k = 0; k < NH; k++) a2 += wr[k] * uvec[k];
    red[t] = a2 * a2;
  }
  __syncthreads();
  for (int d = 128; d > 0; d >>= 1) { if (t < d) red[t] += red[t + d]; __syncthreads(); }
  if (t == 0) itrS[0] = red[0];  // numerator
  __syncthreads();
  float num = itrS[0];
  if (t < 128) red[t] = uvec[t] * uvec[t];
  __syncthreads();
  for (int d = 64; d > 0; d >>= 1) { if (t < d) red[t] += red[t + d]; __syncthreads(); }
  if (t == 0) sig[0] = rsqrtf(num / red[0]);  // 1/sigma
}

// ---------------- P2: per-bucket counting sort; csr = BYTE offsets ---------
__global__ __launch_bounds__(1024) void k_p2(const u32* __restrict__ binned,
                                             const u32* __restrict__ gcur,
                                             uint2* __restrict__ offdeg,
                                             float* __restrict__ dinv,
                                             int* __restrict__ csr) {
  __shared__ u32 hist[BNODE];
  __shared__ u32 loff[BNODE];
  __shared__ u32 cur[BNODE];
  __shared__ u32 stage[CAP];
  int b = blockIdx.x, t = threadIdx.x;
  u32 base = (u32)b * CAP;
  u32 cnt = gcur[b];
  hist[t] = 0;
  __syncthreads();
  for (u32 i = t; i < cnt; i += BNODE) {
    u32 key = binned[base + i];
    atomicAdd(&hist[key >> 17], 1u);
  }
  __syncthreads();
  u32 v = hist[t];
  loff[t] = v;
  __syncthreads();
  for (int d = 1; d < BNODE; d <<= 1) {
    u32 x = loff[t];
    u32 y = (t >= d) ? loff[t - d] : 0u;
    __syncthreads();
    loff[t] = x + y;
    __syncthreads();
  }
  u32 ex = loff[t] - v;
  cur[t] = ex;
  int g = b * BNODE + t;
  if (g < NN) {
    offdeg[g] = make_uint2(base + ex, base + ex + v);
    dinv[g] = rsqrtf((float)(v + 1u));
  }
  __syncthreads();
  if (cnt <= CAP) {
    for (u32 i = t; i < cnt; i += BNODE) {
      u32 key = binned[base + i];
      u32 p = atomicAdd(&cur[key >> 17], 1u);
      stage[p] = key & 0x1FFFFu;
    }
    __syncthreads();
    // store PRE-MULTIPLIED byte offset of hs row: src*256 (row = 128 bf16)
    for (u32 i = t; i < cnt; i += BNODE) csr[base + i] = (int)(stage[i] << 8);
  } else {
    for (u32 i = t; i < cnt; i += BNODE) {
      u32 key = binned[base + i];
      u32 p = atomicAdd(&cur[key >> 17], 1u);
      csr[base + p] = (int)((key & 0x1FFFFu) << 8);
    }
  }
}

// ------- MFMA GEMM (R17-exact): coalesced LDS-staged x, permuted Wt2 -------
__global__ __launch_bounds__(256) void k_mfma(const float* __restrict__ x,
                                              const u16* __restrict__ Wt2,
                                              const float* __restrict__ dinv,
                                              u16* __restrict__ hs) {
  __shared__ __align__(16) char LB[65536];
  int t = threadIdx.x;
  int l = t & 63, w = t >> 6;
  int row0 = blockIdx.x * 128;
  int lr = l & 15;
  int lk = (l >> 4) * 8;

  const float4* x4 = (const float4*)x;
#pragma unroll 8
  for (int i = t; i < 128 * 64; i += 256) {
    int r = i >> 6;
    int cq = i & 63;
    int gr = row0 + r;
    if (gr >= NN) gr = NN - 1;
    float4 v = x4[(size_t)gr * 64 + cq];
    uint2 wv;
    wv.x = (u32)f2bf(v.x) | ((u32)f2bf(v.y) << 16);
    wv.y = (u32)f2bf(v.z) | ((u32)f2bf(v.w) << 16);
    int kb = cq * 8;
    *(uint2*)(LB + r * 512 + (kb ^ ((r & 7) << 4))) = wv;
  }
  __syncthreads();

  int rbase = w * 32;
  f32x4 acc[2][8] = {};
#pragma unroll
  for (int ks = 0; ks < 8; ks++) {
    short8 bfr[8];
#pragma unroll
    for (int n = 0; n < 8; n++)
      bfr[n] = *(const short8*)&Wt2[(size_t)(((n * 8 + ks) * 64) + l) * 8];
    short8 afr[2];
#pragma unroll
    for (int m = 0; m < 2; m++) {
      int r = rbase + m * 16 + lr;
      int kb = (ks * 32 + lk) * 2;
      afr[m] = *(const short8*)(LB + r * 512 + (kb ^ ((r & 7) << 4)));
    }
#pragma unroll
    for (int m = 0; m < 2; m++)
#pragma unroll
      for (int n = 0; n < 8; n++)
        acc[m][n] = __builtin_amdgcn_mfma_f32_16x16x32_bf16(afr[m], bfr[n], acc[m][n], 0, 0, 0);
  }

  __syncthreads();
  u16* tile = (u16*)LB;
#pragma unroll
  for (int m = 0; m < 2; m++) {
    int rbl = w * 32 + m * 16 + (l >> 4) * 4;
    float dv[4];
#pragma unroll
    for (int g = 0; g < 4; g++) {
      int r = row0 + rbl + g;
      dv[g] = (r < NN) ? dinv[r] : 0.f;
    }
#pragma unroll
    for (int n = 0; n < 8; n++)
#pragma unroll
      for (int g = 0; g < 4; g++)
        tile[(rbl + g) * 128 + n * 16 + lr] = f2bf(acc[m][n][g] * dv[g]);
  }
  __syncthreads();
  const uint4* tl = (const uint4*)tile;
  size_t outb = (size_t)row0 * NH;
#pragma unroll
  for (int k = 0; k < 8; k++) {
    int u = t + k * 256;
    if (row0 + (u >> 4) < NN) *(uint4*)&hs[outb + (size_t)u * 8] = tl[u];
  }
}

// -------- gather: R17 shape, 8-deep MLP; csr holds byte offsets ------------
__global__ __launch_bounds__(256) void k_gather(const u16* __restrict__ hs,
                                                const int* __restrict__ csr,
                                                const uint2* __restrict__ offdeg,
                                                const float* __restrict__ dinv,
                                                const float* __restrict__ b,
                                                const float* __restrict__ pa,
                                                const float* __restrict__ sig,
                                                float* __restrict__ out) {
  int wid = threadIdx.x >> 6;
  int lane = threadIdx.x & 63;
  int n = blockIdx.x * 4 + wid;
  if (n >= NN) return;
  uint2 od = offdeg[n];
  u32 s0 = od.x, s1 = od.y;
  const char* hb = (const char*)hs + lane * 4;  // lane byte offset folded once
  float ax, ay;
  {
    u32 u = *(const u32*)(hb + (size_t)n * 256);  // self-loop term
    ax = bflo(u); ay = bfhi(u);
  }
  u32 e = s0;
  for (; e + 8 <= s1; e += 8) {
    int o0 = csr[e],     o1 = csr[e + 1], o2 = csr[e + 2], o3 = csr[e + 3];
    int o4 = csr[e + 4], o5 = csr[e + 5], o6 = csr[e + 6], o7 = csr[e + 7];
    u32 u0 = *(const u32*)(hb + o0);
    u32 u1 = *(const u32*)(hb + o1);
    u32 u2 = *(const u32*)(hb + o2);
    u32 u3 = *(const u32*)(hb + o3);
    u32 u4 = *(const u32*)(hb + o4);
    u32 u5 = *(const u32*)(hb + o5);
    u32 u6 = *(const u32*)(hb + o6);
    u32 u7 = *(const u32*)(hb + o7);
    ax += bflo(u0) + bflo(u1) + bflo(u2) + bflo(u3)
        + bflo(u4) + bflo(u5) + bflo(u6) + bflo(u7);
    ay += bfhi(u0) + bfhi(u1) + bfhi(u2) + bfhi(u3)
        + bfhi(u4) + bfhi(u5) + bfhi(u6) + bfhi(u7);
  }
  for (; e + 4 <= s1; e += 4) {
    int o0 = csr[e], o1 = csr[e + 1], o2 = csr[e + 2], o3 = csr[e + 3];
    u32 u0 = *(const u32*)(hb + o0);
    u32 u1 = *(const u32*)(hb + o1);
    u32 u2 = *(const u32*)(hb + o2);
    u32 u3 = *(const u32*)(hb + o3);
    ax += bflo(u0) + bflo(u1) + bflo(u2) + bflo(u3);
    ay += bfhi(u0) + bfhi(u1) + bfhi(u2) + bfhi(u3);
  }
  for (; e < s1; e++) {
    u32 u = *(const u32*)(hb + csr[e]);
    ax += bflo(u); ay += bfhi(u);
  }
  float dv = dinv[n] * sig[0];
  float2 bb = *(const float2*)&b[lane * 2];
  float a = pa[0];
  float v0 = ax * dv + bb.x;
  float v1 = ay * dv + bb.y;
  float2 o;
  o.x = v0 > 0.f ? v0 : a * v0;
  o.y = v1 > 0.f ? v1 : a * v1;
  *(float2*)&out[(size_t)n * NH + lane * 2] = o;
}

// ---------------- launch ----------------
extern "C" void kernel_launch(void* const* d_in, const int* in_sizes, int n_in,
                              void* d_out, int out_size, void* d_ws, size_t ws_size,
                              hipStream_t stream) {
  const float* x = (const float*)d_in[0];
  const int* ei = (const int*)d_in[1];
  const float* W = (const float*)d_in[2];
  const float* b = (const float*)d_in[3];
  const float* pa = (const float*)d_in[4];
  float* out = (float*)d_out;
  const int* row = ei;
  const int* col = ei + EE;

  char* base = (char*)d_ws;
  size_t o = 0;
  auto alloc = [&](size_t bytes) -> void* {
    void* p = base + o;
    o += (bytes + 63) & ~(size_t)63;
    return p;
  };
  u32* gcur = (u32*)alloc(BK * 4);
  float* sig = (float*)alloc(64);
  float* dinv = (float*)alloc((size_t)NN * 4);
  uint2* offdeg = (uint2*)alloc((size_t)NN * 8);
  u32* binned = (u32*)alloc((size_t)BK * CAP * 4);
  int* csr = (int*)alloc((size_t)BK * CAP * 4);
  u16* Wt2 = (u16*)alloc((size_t)NF * NH * 2);
  u16* hs = (u16*)alloc((size_t)NN * NH * 2);
  (void)ws_size; (void)in_sizes; (void)n_in; (void)out_size;

  hipMemsetAsync(gcur, 0, BK * 4, stream);
  k_p1s<<<NCHUNK + 1, 256, 0, stream>>>(row, col, gcur, binned, W, Wt2, sig);
  k_p2<<<BK, BNODE, 0, stream>>>(binned, gcur, offdeg, dinv, csr);
  k_mfma<<<(NN + 127) / 128, 256, 0, stream>>>(x, Wt2, dinv, hs);
  k_gather<<<(NN + 3) / 4, 256, 0, stream>>>(hs, csr, offdeg, dinv, b, pa, sig, out);
}

// Round 22
// 169.196 us; speedup vs baseline: 1.4604x; 1.0523x over previous
//
#include <hip/hip_runtime.h>

#define NN 100000
#define EE 1600000
#define NF 256
#define NH 128

#define BK 98        // buckets of 1024 nodes
#define BNODE 1024
#define CHUNK 4096
#define NCHUNK ((EE + CHUNK - 1) / CHUNK)  // 391
#define CAP 24576    // per-bucket capacity (counts ~16327±128; huge margin)

typedef unsigned int u32;
typedef unsigned short u16;
typedef __attribute__((ext_vector_type(8))) short short8;
typedef __attribute__((ext_vector_type(4))) float f32x4;

static __device__ __forceinline__ u16 f2bf(float f) {
  u32 u = __float_as_uint(f);
  u32 r = (u + 0x7FFFu + ((u >> 16) & 1u)) >> 16;
  return (u16)r;
}
static __device__ __forceinline__ float bflo(u32 u) { return __uint_as_float(u << 16); }
static __device__ __forceinline__ float bfhi(u32 u) { return __uint_as_float(u & 0xFFFF0000u); }

// ============ k_p1s: block 0 = spectral (dispatched FIRST, overlaps all of
// p1); blocks 1..391 = edge binning. R21's spec-last ordering made spec a
// serial ~35us tail behind the whole p1 phase (k_p1s=73us, occupancy 4%).
__global__ __launch_bounds__(256) void k_p1s(const int* __restrict__ row,
                                             const int* __restrict__ col,
                                             u32* __restrict__ gcur,
                                             u32* __restrict__ binned,
                                             const float* __restrict__ W,
                                             u16* __restrict__ Wt2,
                                             float* __restrict__ sig) {
  __shared__ __align__(16) char SM[69632];
  int t = threadIdx.x;

  if (blockIdx.x != 0) {
    // ---------------- p1: counting-sort edges into padded buckets ----------
    u32* keybuf = (u32*)SM;                                  // 16 KB
    unsigned char* bktbuf = (unsigned char*)(SM + 16384);    // 4 KB
    u32* hist = (u32*)(SM + 20480);
    u32* lstart = (u32*)(SM + 20992);
    u32* lofs = (u32*)(SM + 21504);
    u32* gb = (u32*)(SM + 22016);
    if (t < BK) hist[t] = 0;
    __syncthreads();
    int e0 = (blockIdx.x - 1) * CHUNK;
    int n = min(CHUNK, EE - e0);
    for (int i = t; i < n; i += 256) {
      u32 d = (u32)col[e0 + i];
      atomicAdd(&hist[d >> 10], 1u);
    }
    __syncthreads();
    if (t == 0) {
      u32 s = 0;
      for (int b = 0; b < BK; b++) { lstart[b] = s; lofs[b] = s; s += hist[b]; }
    }
    __syncthreads();
    if (t < BK && hist[t]) gb[t] = (u32)t * CAP + atomicAdd(&gcur[t], hist[t]);
    __syncthreads();
    for (int i = t; i < n; i += 256) {
      u32 d = (u32)col[e0 + i];
      u32 s = (u32)row[e0 + i];
      u32 b = d >> 10;
      u32 p = atomicAdd(&lofs[b], 1u);
      keybuf[p] = ((d & 1023u) << 17) | s;
      bktbuf[p] = (unsigned char)b;
    }
    __syncthreads();
    for (int i = t; i < n; i += 256) {
      u32 b = bktbuf[i];
      binned[gb[b] + ((u32)i - lstart[b])] = keybuf[i];
    }
    return;
  }

  // ---------------- spec: spectral norm + fragment-permuted Wt2 ------------
  char* MB = SM;                          // 64 KB work matrix
  float* diag = (float*)(SM + 65536);     // 128 f
  float* red = (float*)(SM + 66048);      // 256 f
  float* uvec = (float*)(SM + 67072);     // 128 f
  int* jdx = (int*)(SM + 67584);          // 128 i
  float* itrS = (float*)(SM + 68096);
  int* jmS = (int*)(SM + 68100);
  int l = t & 63, w = t >> 6;
  int p = l & 15, q = l >> 4;

  // stage Wt bf16 into LDS (512B rows, XOR-swizzled)
  for (int base = t * 4; base < NF * NH; base += 1024) {
    float4 v = *(const float4*)&W[base];
    int k = base >> 7, c0 = base & 127;
#pragma unroll
    for (int i = 0; i < 4; i++) {
      int c = c0 + i;
      int inner = (k * 2) ^ ((c & 7) << 4);
      *(u16*)(MB + c * 512 + inner) = f2bf(((const float*)&v)[i]);
    }
  }
  __syncthreads();
  // dump Wt2 in fragment-permuted order:
  // Wt2[(((n*8+ks)*64)+l)*8+j] = Wt[c][k], c=n*16+(l&15), k=ks*32+(l>>4)*8+j
  for (int u = t; u < 16384; u += 256) {
    int h = u * 2;
    int n = h >> 12;
    int rem = h & 4095;
    int ks = rem >> 9;
    int rem2 = rem & 511;
    int ll = rem2 >> 3;
    int j = rem2 & 7;
    int c = n * 16 + (ll & 15);
    int k = ks * 32 + ((ll >> 4) << 3) + j;
    ((u32*)Wt2)[u] = *(u32*)(MB + c * 512 + ((2 * k) ^ ((c & 7) << 4)));
  }

  // gram via MFMA
  f32x4 acc[2][8] = {};
#pragma unroll
  for (int ks = 0; ks < 8; ks++) {
    int kb = (ks * 32 + q * 8) * 2;
    short8 afr[2], bfr[8];
#pragma unroll
    for (int m = 0; m < 2; m++) {
      int ra = w * 32 + m * 16 + p;
      afr[m] = *(const short8*)(MB + ra * 512 + (kb ^ ((ra & 7) << 4)));
    }
#pragma unroll
    for (int n = 0; n < 8; n++) {
      int r = n * 16 + p;
      bfr[n] = *(const short8*)(MB + r * 512 + (kb ^ ((r & 7) << 4)));
    }
#pragma unroll
    for (int m = 0; m < 2; m++)
#pragma unroll
      for (int n = 0; n < 8; n++)
        acc[m][n] = __builtin_amdgcn_mfma_f32_16x16x32_bf16(afr[m], bfr[n], acc[m][n], 0, 0, 0);
  }
#pragma unroll
  for (int m = 0; m < 2; m++)
#pragma unroll
    for (int n = 0; n < 8; n++)
#pragma unroll
      for (int g = 0; g < 4; g++) {
        int r = w * 32 + m * 16 + q * 4 + g;
        int c = n * 16 + p;
        if (r == c) diag[r] = acc[m][n][g];
      }
  __syncthreads();
  if (t < 128) red[t] = diag[t];
  __syncthreads();
  for (int d = 64; d > 0; d >>= 1) { if (t < d) red[t] += red[t + d]; __syncthreads(); }
  if (t == 0) itrS[0] = 1.0f / red[0];
  __syncthreads();
  {
    float itr = itrS[0];
#pragma unroll
    for (int m = 0; m < 2; m++)
#pragma unroll
      for (int n = 0; n < 8; n++)
#pragma unroll
        for (int g = 0; g < 4; g++) {
          int r = w * 32 + m * 16 + q * 4 + g;
          int c = n * 16 + p;
          *(u16*)(MB + r * 256 + ((c * 2) ^ ((r & 7) << 4))) = f2bf(acc[m][n][g] * itr);
        }
  }

  // 8 trace-normalized MFMA squarings (bf16, in LDS)
  char* src = MB;
  char* dst = MB + 32768;
  for (int s = 0; s < 8; s++) {
    __syncthreads();
    f32x4 mac[2][8] = {};
#pragma unroll
    for (int ks = 0; ks < 4; ks++) {
      int kb = (ks * 32 + q * 8) * 2;
      short8 afr[2], bfr[8];
#pragma unroll
      for (int m = 0; m < 2; m++) {
        int ra = w * 32 + m * 16 + p;
        afr[m] = *(const short8*)(src + ra * 256 + (kb ^ ((ra & 7) << 4)));
      }
#pragma unroll
      for (int n = 0; n < 8; n++) {
        int r = n * 16 + p;
        bfr[n] = *(const short8*)(src + r * 256 + (kb ^ ((r & 7) << 4)));
      }
#pragma unroll
      for (int m = 0; m < 2; m++)
#pragma unroll
        for (int n = 0; n < 8; n++)
          mac[m][n] = __builtin_amdgcn_mfma_f32_16x16x32_bf16(afr[m], bfr[n], mac[m][n], 0, 0, 0);
    }
#pragma unroll
    for (int m = 0; m < 2; m++)
#pragma unroll
      for (int n = 0; n < 8; n++)
#pragma unroll
        for (int g = 0; g < 4; g++) {
          int r = w * 32 + m * 16 + q * 4 + g;
          int c = n * 16 + p;
          if (r == c) diag[r] = mac[m][n][g];
        }
    __syncthreads();
    if (t < 128) red[t] = diag[t];
    __syncthreads();
    for (int d = 64; d > 0; d >>= 1) { if (t < d) red[t] += red[t + d]; __syncthreads(); }
    if (t == 0) itrS[0] = 1.0f / red[0];
    __syncthreads();
    float it2 = itrS[0];
#pragma unroll
    for (int m = 0; m < 2; m++)
#pragma unroll
      for (int n = 0; n < 8; n++)
#pragma unroll
        for (int g = 0; g < 4; g++) {
          int r = w * 32 + m * 16 + q * 4 + g;
          int c = n * 16 + p;
          *(u16*)(dst + r * 256 + ((c * 2) ^ ((r & 7) << 4))) = f2bf(mac[m][n][g] * it2);
        }
    char* tmp = src; src = dst; dst = tmp;
  }
  __syncthreads();

  // parallel argmax of diag
  if (t < 128) { red[t] = diag[t]; jdx[t] = t; }
  __syncthreads();
  for (int d = 64; d > 0; d >>= 1) {
    if (t < d && red[t + d] > red[t]) { red[t] = red[t + d]; jdx[t] = jdx[t + d]; }
    __syncthreads();
  }
  if (t == 0) jmS[0] = jdx[0];
  __syncthreads();
  int jm = jmS[0];
  if (t < 128) {
    u16 hv = *(u16*)(src + jm * 256 + ((t * 2) ^ ((jm & 7) << 4)));
    uvec[t] = __uint_as_float(((u32)hv) << 16);
  }
  __syncthreads();
  // Rayleigh on original W: lambda1 = |W u|^2 / |u|^2
  {
    float a2 = 0.f;
    const float* wr = &W[t * NH];
    for (int k = 0; k < NH; k++) a2 += wr[k] * uvec[k];
    red[t] = a2 * a2;
  }
  __syncthreads();
  for (int d = 128; d > 0; d >>= 1) { if (t < d) red[t] += red[t + d]; __syncthreads(); }
  if (t == 0) itrS[0] = red[0];  // numerator
  __syncthreads();
  float num = itrS[0];
  if (t < 128) red[t] = uvec[t] * uvec[t];
  __syncthreads();
  for (int d = 64; d > 0; d >>= 1) { if (t < d) red[t] += red[t + d]; __syncthreads(); }
  if (t == 0) sig[0] = rsqrtf(num / red[0]);  // 1/sigma
}

// ---------------- P2: per-bucket counting sort; csr = BYTE offsets ---------
__global__ __launch_bounds__(1024) void k_p2(const u32* __restrict__ binned,
                                             const u32* __restrict__ gcur,
                                             uint2* __restrict__ offdeg,
                                             float* __restrict__ dinv,
                                             int* __restrict__ csr) {
  __shared__ u32 hist[BNODE];
  __shared__ u32 loff[BNODE];
  __shared__ u32 cur[BNODE];
  __shared__ u32 stage[CAP];
  int b = blockIdx.x, t = threadIdx.x;
  u32 base = (u32)b * CAP;
  u32 cnt = gcur[b];
  hist[t] = 0;
  __syncthreads();
  for (u32 i = t; i < cnt; i += BNODE) {
    u32 key = binned[base + i];
    atomicAdd(&hist[key >> 17], 1u);
  }
  __syncthreads();
  u32 v = hist[t];
  loff[t] = v;
  __syncthreads();
  for (int d = 1; d < BNODE; d <<= 1) {
    u32 x = loff[t];
    u32 y = (t >= d) ? loff[t - d] : 0u;
    __syncthreads();
    loff[t] = x + y;
    __syncthreads();
  }
  u32 ex = loff[t] - v;
  cur[t] = ex;
  int g = b * BNODE + t;
  if (g < NN) {
    offdeg[g] = make_uint2(base + ex, base + ex + v);
    dinv[g] = rsqrtf((float)(v + 1u));
  }
  __syncthreads();
  if (cnt <= CAP) {
    for (u32 i = t; i < cnt; i += BNODE) {
      u32 key = binned[base + i];
      u32 p = atomicAdd(&cur[key >> 17], 1u);
      stage[p] = key & 0x1FFFFu;
    }
    __syncthreads();
    // store PRE-MULTIPLIED byte offset of hs row: src*256 (row = 128 bf16)
    for (u32 i = t; i < cnt; i += BNODE) csr[base + i] = (int)(stage[i] << 8);
  } else {
    for (u32 i = t; i < cnt; i += BNODE) {
      u32 key = binned[base + i];
      u32 p = atomicAdd(&cur[key >> 17], 1u);
      csr[base + p] = (int)((key & 0x1FFFFu) << 8);
    }
  }
}

// ------- MFMA GEMM (R17-exact): coalesced LDS-staged x, permuted Wt2 -------
__global__ __launch_bounds__(256) void k_mfma(const float* __restrict__ x,
                                              const u16* __restrict__ Wt2,
                                              const float* __restrict__ dinv,
                                              u16* __restrict__ hs) {
  __shared__ __align__(16) char LB[65536];
  int t = threadIdx.x;
  int l = t & 63, w = t >> 6;
  int row0 = blockIdx.x * 128;
  int lr = l & 15;
  int lk = (l >> 4) * 8;

  const float4* x4 = (const float4*)x;
#pragma unroll 8
  for (int i = t; i < 128 * 64; i += 256) {
    int r = i >> 6;
    int cq = i & 63;
    int gr = row0 + r;
    if (gr >= NN) gr = NN - 1;
    float4 v = x4[(size_t)gr * 64 + cq];
    uint2 wv;
    wv.x = (u32)f2bf(v.x) | ((u32)f2bf(v.y) << 16);
    wv.y = (u32)f2bf(v.z) | ((u32)f2bf(v.w) << 16);
    int kb = cq * 8;
    *(uint2*)(LB + r * 512 + (kb ^ ((r & 7) << 4))) = wv;
  }
  __syncthreads();

  int rbase = w * 32;
  f32x4 acc[2][8] = {};
#pragma unroll
  for (int ks = 0; ks < 8; ks++) {
    short8 bfr[8];
#pragma unroll
    for (int n = 0; n < 8; n++)
      bfr[n] = *(const short8*)&Wt2[(size_t)(((n * 8 + ks) * 64) + l) * 8];
    short8 afr[2];
#pragma unroll
    for (int m = 0; m < 2; m++) {
      int r = rbase + m * 16 + lr;
      int kb = (ks * 32 + lk) * 2;
      afr[m] = *(const short8*)(LB + r * 512 + (kb ^ ((r & 7) << 4)));
    }
#pragma unroll
    for (int m = 0; m < 2; m++)
#pragma unroll
      for (int n = 0; n < 8; n++)
        acc[m][n] = __builtin_amdgcn_mfma_f32_16x16x32_bf16(afr[m], bfr[n], acc[m][n], 0, 0, 0);
  }

  __syncthreads();
  u16* tile = (u16*)LB;
#pragma unroll
  for (int m = 0; m < 2; m++) {
    int rbl = w * 32 + m * 16 + (l >> 4) * 4;
    float dv[4];
#pragma unroll
    for (int g = 0; g < 4; g++) {
      int r = row0 + rbl + g;
      dv[g] = (r < NN) ? dinv[r] : 0.f;
    }
#pragma unroll
    for (int n = 0; n < 8; n++)
#pragma unroll
      for (int g = 0; g < 4; g++)
        tile[(rbl + g) * 128 + n * 16 + lr] = f2bf(acc[m][n][g] * dv[g]);
  }
  __syncthreads();
  const uint4* tl = (const uint4*)tile;
  size_t outb = (size_t)row0 * NH;
#pragma unroll
  for (int k = 0; k < 8; k++) {
    int u = t + k * 256;
    if (row0 + (u >> 4) < NN) *(uint4*)&hs[outb + (size_t)u * 8] = tl[u];
  }
}

// -------- gather: R21-exact (wave per node, 8-deep, byte-offset csr) -------
__global__ __launch_bounds__(256) void k_gather(const u16* __restrict__ hs,
                                                const int* __restrict__ csr,
                                                const uint2* __restrict__ offdeg,
                                                const float* __restrict__ dinv,
                                                const float* __restrict__ b,
                                                const float* __restrict__ pa,
                                                const float* __restrict__ sig,
                                                float* __restrict__ out) {
  int wid = threadIdx.x >> 6;
  int lane = threadIdx.x & 63;
  int n = blockIdx.x * 4 + wid;
  if (n >= NN) return;
  uint2 od = offdeg[n];
  u32 s0 = od.x, s1 = od.y;
  const char* hb = (const char*)hs + lane * 4;
  float ax, ay;
  {
    u32 u = *(const u32*)(hb + (size_t)n * 256);  // self-loop term
    ax = bflo(u); ay = bfhi(u);
  }
  u32 e = s0;
  for (; e + 8 <= s1; e += 8) {
    int o0 = csr[e],     o1 = csr[e + 1], o2 = csr[e + 2], o3 = csr[e + 3];
    int o4 = csr[e + 4], o5 = csr[e + 5], o6 = csr[e + 6], o7 = csr[e + 7];
    u32 u0 = *(const u32*)(hb + o0);
    u32 u1 = *(const u32*)(hb + o1);
    u32 u2 = *(const u32*)(hb + o2);
    u32 u3 = *(const u32*)(hb + o3);
    u32 u4 = *(const u32*)(hb + o4);
    u32 u5 = *(const u32*)(hb + o5);
    u32 u6 = *(const u32*)(hb + o6);
    u32 u7 = *(const u32*)(hb + o7);
    ax += bflo(u0) + bflo(u1) + bflo(u2) + bflo(u3)
        + bflo(u4) + bflo(u5) + bflo(u6) + bflo(u7);
    ay += bfhi(u0) + bfhi(u1) + bfhi(u2) + bfhi(u3)
        + bfhi(u4) + bfhi(u5) + bfhi(u6) + bfhi(u7);
  }
  for (; e + 4 <= s1; e += 4) {
    int o0 = csr[e], o1 = csr[e + 1], o2 = csr[e + 2], o3 = csr[e + 3];
    u32 u0 = *(const u32*)(hb + o0);
    u32 u1 = *(const u32*)(hb + o1);
    u32 u2 = *(const u32*)(hb + o2);
    u32 u3 = *(const u32*)(hb + o3);
    ax += bflo(u0) + bflo(u1) + bflo(u2) + bflo(u3);
    ay += bfhi(u0) + bfhi(u1) + bfhi(u2) + bfhi(u3);
  }
  for (; e < s1; e++) {
    u32 u = *(const u32*)(hb + csr[e]);
    ax += bflo(u); ay += bfhi(u);
  }
  float dv = dinv[n] * sig[0];
  float2 bb = *(const float2*)&b[lane * 2];
  float a = pa[0];
  float v0 = ax * dv + bb.x;
  float v1 = ay * dv + bb.y;
  float2 o;
  o.x = v0 > 0.f ? v0 : a * v0;
  o.y = v1 > 0.f ? v1 : a * v1;
  *(float2*)&out[(size_t)n * NH + lane * 2] = o;
}

// ---------------- launch ----------------
extern "C" void kernel_launch(void* const* d_in, const int* in_sizes, int n_in,
                              void* d_out, int out_size, void* d_ws, size_t ws_size,
                              hipStream_t stream) {
  const float* x = (const float*)d_in[0];
  const int* ei = (const int*)d_in[1];
  const float* W = (const float*)d_in[2];
  const float* b = (const float*)d_in[3];
  const float* pa = (const float*)d_in[4];
  float* out = (float*)d_out;
  const int* row = ei;
  const int* col = ei + EE;

  char* base = (char*)d_ws;
  size_t o = 0;
  auto alloc = [&](size_t bytes) -> void* {
    void* p = base + o;
    o += (bytes + 63) & ~(size_t)63;
    return p;
  };
  u32* gcur = (u32*)alloc(BK * 4);
  float* sig = (float*)alloc(64);
  float* dinv = (float*)alloc((size_t)NN * 4);
  uint2* offdeg = (uint2*)alloc((size_t)NN * 8);
  u32* binned = (u32*)alloc((size_t)BK * CAP * 4);
  int* csr = (int*)alloc((size_t)BK * CAP * 4);
  u16* Wt2 = (u16*)alloc((size_t)NF * NH * 2);
  u16* hs = (u16*)alloc((size_t)NN * NH * 2);
  (void)ws_size; (void)in_sizes; (void)n_in; (void)out_size;

  hipMemsetAsync(gcur, 0, BK * 4, stream);
  k_p1s<<<NCHUNK + 1, 256, 0, stream>>>(row, col, gcur, binned, W, Wt2, sig);
  k_p2<<<BK, BNODE, 0, stream>>>(binned, gcur, offdeg, dinv, csr);
  k_mfma<<<(NN + 127) / 128, 256, 0, stream>>>(x, Wt2, dinv, hs);
  k_gather<<<(NN + 3) / 4, 256, 0, stream>>>(hs, csr, offdeg, dinv, b, pa, sig, out);
}